// Round 2
// baseline (657.434 us; speedup 1.0000x reference)
//
#include <hip/hip_runtime.h>
#include <hip/hip_bf16.h>
#include <cstdint>

#define SP 16384

// ---------------- K1: grouped conv 3x3x3 (groups=4) + BN1 + ReLU -> k ----------------
__global__ __launch_bounds__(256) void k1_gconv(
    const float* __restrict__ x, const float* __restrict__ wkey,
    const float* __restrict__ bn1s, const float* __restrict__ bn1b,
    float* __restrict__ kout)
{
  const int ocb = blockIdx.x;          // 24 blocks of 8 oc
  const int tile = blockIdx.y;         // 16 = 4 z-tiles x 4 y-tiles
  const int b = blockIdx.z;
  const int oc0 = ocb * 8;
  const int g = oc0 / 48;
  const int z0 = (tile >> 2) * 4, y0 = (tile & 3) * 8;
  const int tid = threadIdx.x;
  const int tx = (tid & 7) * 4;
  const int ty = (tid >> 3) & 7;
  const int tz = tid >> 6;

  __shared__ __align__(16) float xs[2][6][10][35];   // stride 35: ~2-way banks (free)
  __shared__ __align__(16) float ws[2][27][8];       // [ic][tap][oc]

  float acc[8][4];
  #pragma unroll
  for (int o = 0; o < 8; ++o)
    #pragma unroll
    for (int i = 0; i < 4; ++i) acc[o][i] = 0.f;

  for (int icp = 0; icp < 24; ++icp) {               // 2 input channels per chunk
    __syncthreads();
    // stage x slab: 2 ch x 6z x 10y x 34x (zero-padded borders)
    for (int e = tid; e < 4080; e += 256) {
      int cc = e / 2040; int r = e - cc * 2040;
      int zz = r / 340;  int r2 = r - zz * 340;
      int yy = r2 / 34;  int xx = r2 - yy * 34;
      int gz = z0 - 1 + zz, gy = y0 - 1 + yy, gx = xx - 1;
      float v = 0.f;
      if (gz >= 0 && gz < 16 && gy >= 0 && gy < 32 && gx >= 0 && gx < 32)
        v = x[(((size_t)b * 192 + g * 48 + icp * 2 + cc) << 14) + (gz << 10) + (gy << 5) + gx];
      xs[cc][zz][yy][xx] = v;
    }
    // stage weights transposed: ws[ic][tap][oc]
    for (int e = tid; e < 432; e += 256) {
      int oci = e / 54; int r = e - oci * 54;
      int ici = r / 27; int ti = r - ici * 27;
      ws[ici][ti][oci] = wkey[((size_t)(oc0 + oci) * 48 + icp * 2 + ici) * 27 + ti];
    }
    __syncthreads();
    #pragma unroll
    for (int icc = 0; icc < 2; ++icc) {
      #pragma unroll
      for (int dz = 0; dz < 3; ++dz) {
        #pragma unroll
        for (int dy = 0; dy < 3; ++dy) {
          float xv[6];
          #pragma unroll
          for (int j = 0; j < 6; ++j) xv[j] = xs[icc][tz + dz][ty + dy][tx + j];
          #pragma unroll
          for (int dx = 0; dx < 3; ++dx) {
            const float* wp = &ws[icc][dz * 9 + dy * 3 + dx][0];
            float4 wa = *(const float4*)wp;
            float4 wb = *(const float4*)(wp + 4);
            float w8[8] = {wa.x, wa.y, wa.z, wa.w, wb.x, wb.y, wb.z, wb.w};
            #pragma unroll
            for (int o = 0; o < 8; ++o)
              #pragma unroll
              for (int xi = 0; xi < 4; ++xi)
                acc[o][xi] += w8[o] * xv[dx + xi];
          }
        }
      }
    }
  }
  const int z = z0 + tz, y = y0 + ty;
  #pragma unroll
  for (int o = 0; o < 8; ++o) {
    float sc = bn1s[oc0 + o], bb = bn1b[oc0 + o];
    float4 r;
    r.x = fmaxf(acc[o][0] * sc + bb, 0.f);
    r.y = fmaxf(acc[o][1] * sc + bb, 0.f);
    r.z = fmaxf(acc[o][2] * sc + bb, 0.f);
    r.w = fmaxf(acc[o][3] * sc + bb, 0.f);
    *(float4*)&kout[(((size_t)b * 192 + oc0 + o) << 14) + (z << 10) + (y << 5) + tx] = r;
  }
}

// ---------------- generic fp32 GEMM: out[b][m][n] = epi(A[m][:] . In[b][:][n]) ----------
// EPI: 0 = relu(v*sc+bi), 1 = v*sc+bi, 2 = v+bi
template<int KTOT, int EPI>
__global__ __launch_bounds__(256) void gemm_k(
    const float* __restrict__ A,
    const float* __restrict__ src0, const float* __restrict__ src1, int c0,
    const float* __restrict__ sc, const float* __restrict__ bi,
    float* __restrict__ out, int M)
{
  const int n0 = blockIdx.x * 128;
  const int m_base = blockIdx.y * 96;
  const int b = blockIdx.z;
  const int tid = threadIdx.x;
  const int tn = tid & 15, tm = tid >> 4;
  __shared__ __align__(16) float Ws[16][96];
  __shared__ __align__(16) float Is[16][128];
  float acc[6][8] = {};
  for (int kc = 0; kc < KTOT; kc += 16) {
    __syncthreads();
    #pragma unroll
    for (int i = 0; i < 2; ++i) {
      int idx = tid + i * 256;
      int r = idx >> 5, c4 = idx & 31;
      int ch = kc + r;
      const float* s = (ch < c0) ? src0 + (((size_t)b * c0 + ch) << 14)
                                 : src1 + (((size_t)(b * 192) + (ch - c0)) << 14);
      *(float4*)&Is[r][c4 * 4] = *(const float4*)(s + n0 + c4 * 4);
    }
    for (int idx = tid; idx < 384; idx += 256) {
      int m = idx >> 2, kq = idx & 3;
      int gm = m_base + m;
      float4 w = {0.f, 0.f, 0.f, 0.f};
      if (gm < M) w = *(const float4*)(A + (size_t)gm * KTOT + kc + kq * 4);
      Ws[kq * 4 + 0][m] = w.x;
      Ws[kq * 4 + 1][m] = w.y;
      Ws[kq * 4 + 2][m] = w.z;
      Ws[kq * 4 + 3][m] = w.w;
    }
    __syncthreads();
    #pragma unroll
    for (int kk = 0; kk < 16; ++kk) {
      float av[6];
      #pragma unroll
      for (int i = 0; i < 6; ++i) av[i] = Ws[kk][tm * 6 + i];
      float4 b0 = *(const float4*)&Is[kk][tn * 8];
      float4 b1 = *(const float4*)&Is[kk][tn * 8 + 4];
      float bv[8] = {b0.x, b0.y, b0.z, b0.w, b1.x, b1.y, b1.z, b1.w};
      #pragma unroll
      for (int i = 0; i < 6; ++i)
        #pragma unroll
        for (int j = 0; j < 8; ++j)
          acc[i][j] += av[i] * bv[j];
    }
  }
  #pragma unroll
  for (int i = 0; i < 6; ++i) {
    int gm = m_base + tm * 6 + i;
    if (gm >= M) continue;
    float scv = (EPI == 2) ? 1.f : sc[gm];
    float biv = bi[gm];
    float r[8];
    #pragma unroll
    for (int j = 0; j < 8; ++j) {
      float t = acc[i][j] * scv + biv;
      r[j] = (EPI == 0) ? fmaxf(t, 0.f) : t;
    }
    float* op = out + (((size_t)b * M + gm) << 14) + n0 + tn * 8;
    float4 r0 = {r[0], r[1], r[2], r[3]}, r1 = {r[4], r[5], r[6], r[7]};
    *(float4*)op = r0;
    *(float4*)(op + 4) = r1;
  }
}

// ---------------- K3b: GroupNorm stats (sum, sumsq) per (b, group of 9 ch) -------------
__global__ __launch_bounds__(256) void k3b_gnstats(const float* __restrict__ wraw,
                                                   float* __restrict__ gsums)
{
  const int chunk = blockIdx.x, g = blockIdx.y, b = blockIdx.z;
  const float4* p = (const float4*)(wraw + (((size_t)b * 216 + g * 9) << 14));
  float s1 = 0.f, s2 = 0.f;
  const int base = chunk * 4608 + threadIdx.x;
  #pragma unroll 4
  for (int i = 0; i < 18; ++i) {
    float4 v = p[base + i * 256];
    s1 += v.x + v.y + v.z + v.w;
    s2 += v.x * v.x + v.y * v.y + v.z * v.z + v.w * v.w;
  }
  #pragma unroll
  for (int o = 32; o > 0; o >>= 1) { s1 += __shfl_down(s1, o); s2 += __shfl_down(s2, o); }
  __shared__ float ps[4][2];
  int lane = threadIdx.x & 63, w = threadIdx.x >> 6;
  if (lane == 0) { ps[w][0] = s1; ps[w][1] = s2; }
  __syncthreads();
  if (threadIdx.x == 0) {
    float t1 = ps[0][0] + ps[1][0] + ps[2][0] + ps[3][0];
    float t2 = ps[0][1] + ps[1][1] + ps[2][1] + ps[3][1];
    atomicAdd(&gsums[(b * 24 + g) * 2 + 0], t1);
    atomicAdd(&gsums[(b * 24 + g) * 2 + 1], t2);
  }
}

// ---------------- K4: dynamic 3x3x3 conv + BN4 + SiLU -> x2 (stored in d_out) ----------
__global__ __launch_bounds__(256) void k4_dynconv(
    const float* __restrict__ wraw, const float* __restrict__ vbuf,
    const float* __restrict__ gsums,
    const float* __restrict__ gns, const float* __restrict__ gnb,
    const float* __restrict__ bn4s, const float* __restrict__ bn4b,
    float* __restrict__ x2)
{
  const int tile = blockIdx.x;
  const int z0 = (tile >> 2) * 4, y0 = (tile & 3) * 8;
  const int cs = blockIdx.y;
  const int b = blockIdx.z >> 3, gw = blockIdx.z & 7;
  const int tid = threadIdx.x;
  const int tx = (tid & 7) * 4, ty = (tid >> 3) & 7, tz = tid >> 6;

  __shared__ __align__(16) float vs[6][6][10][35];
  __shared__ __align__(16) float wls[3][1024];

  float mu[3], rs[3];
  #pragma unroll
  for (int j = 0; j < 3; ++j) {
    int gr = gw * 3 + j;
    float m1 = gsums[(b * 24 + gr) * 2 + 0] * (1.f / 147456.f);
    float m2 = gsums[(b * 24 + gr) * 2 + 1] * (1.f / 147456.f);
    mu[j] = m1;
    rs[j] = rsqrtf(m2 - m1 * m1 + 1e-5f);
  }
  const int c0 = gw * 24 + cs * 6;
  for (int e = tid; e < 6 * 2040; e += 256) {
    int cc = e / 2040; int r = e - cc * 2040;
    int zz = r / 340;  int r2 = r - zz * 340;
    int yy = r2 / 34;  int xx = r2 - yy * 34;
    int gz = z0 - 1 + zz, gy = y0 - 1 + yy, gx = xx - 1;
    float val = 0.f;
    if (gz >= 0 && gz < 16 && gy >= 0 && gy < 32 && gx >= 0 && gx < 32)
      val = vbuf[(((size_t)b * 192 + c0 + cc) << 14) + (gz << 10) + (gy << 5) + gx];
    vs[cc][zz][yy][xx] = val;
  }
  float acc[6][4] = {};
  for (int chnk = 0; chnk < 9; ++chnk) {             // (dz,dy)
    const int dz = chnk / 3, dy = chnk - dz * 3;
    __syncthreads();                                 // covers vs stage (1st) + wls reuse
    #pragma unroll
    for (int i = 0; i < 3; ++i) {                    // stage 3 normalized weight planes
      int e4 = tid + i * 256;
      int idxi = e4 >> 8, s4 = e4 & 255;
      int zz = s4 >> 6, rem = s4 & 63, yy = rem >> 3, x4 = rem & 7;
      int cw = gw * 27 + chnk * 3 + idxi;
      float scw = rs[dz] * gns[cw];
      float shw = gnb[cw] - mu[dz] * scw;
      float4 wv = *(const float4*)&wraw[(((size_t)b * 216 + cw) << 14) +
                                        ((z0 + zz) << 10) + ((y0 + yy) << 5) + (x4 << 2)];
      float4 o4;
      o4.x = wv.x * scw + shw; o4.y = wv.y * scw + shw;
      o4.z = wv.z * scw + shw; o4.w = wv.w * scw + shw;
      int row = zz * 8 + yy;
      ((float4*)&wls[idxi][0])[(row << 3) | (x4 ^ (row & 7))] = o4;   // XOR swizzle
    }
    __syncthreads();
    float xv[6][6];
    #pragma unroll
    for (int cc = 0; cc < 6; ++cc)
      #pragma unroll
      for (int j = 0; j < 6; ++j) xv[cc][j] = vs[cc][tz + dz][ty + dy][tx + j];
    const int row = tz * 8 + ty;
    #pragma unroll
    for (int dxi = 0; dxi < 3; ++dxi) {
      float4 wv = ((const float4*)&wls[dxi][0])[(row << 3) | ((tx >> 2) ^ (row & 7))];
      float w4[4] = {wv.x, wv.y, wv.z, wv.w};
      #pragma unroll
      for (int cc = 0; cc < 6; ++cc)
        #pragma unroll
        for (int xi = 0; xi < 4; ++xi)
          acc[cc][xi] += w4[xi] * xv[cc][dxi + xi];
    }
  }
  #pragma unroll
  for (int cc = 0; cc < 6; ++cc) {
    int c = c0 + cc;
    float scv = bn4s[c], bb = bn4b[c];
    float4 r;
    float t;
    t = acc[cc][0] * scv + bb; r.x = t / (1.f + expf(-t));
    t = acc[cc][1] * scv + bb; r.y = t / (1.f + expf(-t));
    t = acc[cc][2] * scv + bb; r.z = t / (1.f + expf(-t));
    t = acc[cc][3] * scv + bb; r.w = t / (1.f + expf(-t));
    *(float4*)&x2[(((size_t)b * 192 + c) << 14) + ((z0 + tz) << 10) + ((y0 + ty) << 5) + tx] = r;
  }
}

// ---------------- K5a: gap[b][c] = mean_s(x2 + k) ----------------
__global__ __launch_bounds__(256) void k5a_gap(const float* __restrict__ x2,
                                               const float* __restrict__ k,
                                               float* __restrict__ gap)
{
  const int bc = blockIdx.x;
  const float4* p1 = (const float4*)(x2 + ((size_t)bc << 14));
  const float4* p2 = (const float4*)(k + ((size_t)bc << 14));
  float s = 0.f;
  for (int i = threadIdx.x; i < 4096; i += 256) {
    float4 a = p1[i], b2 = p2[i];
    s += (a.x + b2.x) + (a.y + b2.y) + (a.z + b2.z) + (a.w + b2.w);
  }
  #pragma unroll
  for (int o = 32; o > 0; o >>= 1) s += __shfl_down(s, o);
  __shared__ float ps[4];
  if ((threadIdx.x & 63) == 0) ps[threadIdx.x >> 6] = s;
  __syncthreads();
  if (threadIdx.x == 0) gap[bc] = (ps[0] + ps[1] + ps[2] + ps[3]) * (1.f / 16384.f);
}

// ---------------- K5b: SE head -> per-channel softmax pair ----------------
__global__ __launch_bounds__(256) void k5b_se(
    const float* __restrict__ gap,
    const float* __restrict__ wse1, const float* __restrict__ bse1,
    const float* __restrict__ bnses, const float* __restrict__ bnseb,
    const float* __restrict__ wse2, const float* __restrict__ bse2,
    float* __restrict__ attnb)
{
  __shared__ float g[384];
  __shared__ float h[192];
  __shared__ float at[768];
  const int tid = threadIdx.x;
  for (int t = tid; t < 384; t += 256) g[t] = gap[t];   // FIXED: was if(tid<384) with 256 threads
  __syncthreads();
  if (tid < 192) {
    int b = tid / 96, o = tid - b * 96;
    float s = 0.f;
    for (int i = 0; i < 192; ++i) s += wse1[o * 192 + i] * g[b * 192 + i];
    s = (s + bse1[o]) * bnses[o] + bnseb[o];
    h[tid] = fmaxf(s, 0.f);
  }
  __syncthreads();
  for (int t = tid; t < 768; t += 256) {
    int b = t / 384, o = t - b * 384;
    float s = 0.f;
    for (int i = 0; i < 96; ++i) s += wse2[o * 96 + i] * h[b * 96 + i];
    at[t] = s + bse2[o];
  }
  __syncthreads();
  for (int t = tid; t < 384; t += 256) {
    int b = t / 192, c = t - b * 192;
    float a0 = at[b * 384 + 2 * c], a1 = at[b * 384 + 2 * c + 1];
    float m = fmaxf(a0, a1);
    float e0 = expf(a0 - m), e1 = expf(a1 - m);
    float inv = 1.f / (e0 + e1);
    attnb[t * 2 + 0] = e0 * inv;
    attnb[t * 2 + 1] = e1 * inv;
  }
}

// ---------------- K6: out = x2*p0 + k*p1 (in place: io holds x2) ----------------
__global__ __launch_bounds__(256) void k6_combine(const float* __restrict__ k,
                                                  const float* __restrict__ attnb,
                                                  float* io)
{
  const int i4 = blockIdx.x * 256 + threadIdx.x;
  const int bc = i4 >> 12;
  float p0 = attnb[bc * 2 + 0], p1 = attnb[bc * 2 + 1];
  float4 a = ((const float4*)io)[i4];
  float4 kk = ((const float4*)k)[i4];
  float4 r;
  r.x = a.x * p0 + kk.x * p1;
  r.y = a.y * p0 + kk.y * p1;
  r.z = a.z * p0 + kk.z * p1;
  r.w = a.w * p0 + kk.w * p1;
  ((float4*)io)[i4] = r;
}

extern "C" void kernel_launch(void* const* d_in, const int* in_sizes, int n_in,
                              void* d_out, int out_size, void* d_ws, size_t ws_size,
                              hipStream_t stream) {
  const float* x     = (const float*)d_in[0];
  const float* wkey  = (const float*)d_in[1];
  const float* bn1s  = (const float*)d_in[2];
  const float* bn1b  = (const float*)d_in[3];
  const float* we1   = (const float*)d_in[4];
  const float* bn2s  = (const float*)d_in[5];
  const float* bn2b  = (const float*)d_in[6];
  const float* we2   = (const float*)d_in[7];
  const float* be2   = (const float*)d_in[8];
  const float* gns   = (const float*)d_in[9];
  const float* gnb   = (const float*)d_in[10];
  const float* wc1   = (const float*)d_in[11];
  const float* bn3s  = (const float*)d_in[12];
  const float* bn3b  = (const float*)d_in[13];
  const float* bn4s  = (const float*)d_in[14];
  const float* bn4b  = (const float*)d_in[15];
  const float* wse1  = (const float*)d_in[16];
  const float* bse1  = (const float*)d_in[17];
  const float* bnses = (const float*)d_in[18];
  const float* bnseb = (const float*)d_in[19];
  const float* wse2  = (const float*)d_in[20];
  const float* bse2  = (const float*)d_in[21];

  float* ws    = (float*)d_ws;
  float* kbuf  = ws + 0;          // 2*192*SP = 6291456
  float* ebuf  = ws + 6291456;    // 2* 96*SP = 3145728
  float* wrbuf = ws + 9437184;    // 2*216*SP = 7077888
  float* vbuf  = ws + 16515072;   // 2*192*SP = 6291456
  float* gsums = ws + 22806528;   // 96
  float* gap   = ws + 22806624;   // 384
  float* attnb = ws + 22807008;   // 768
  float* x2    = (float*)d_out;   // x2 lives in d_out; K6 finishes in place

  hipMemsetAsync(gsums, 0, 96 * sizeof(float), stream);

  k1_gconv<<<dim3(24, 16, 2), 256, 0, stream>>>(x, wkey, bn1s, bn1b, kbuf);
  // v = bn3(w_c1 @ x)            (M=192, K=192, no relu)
  gemm_k<192, 1><<<dim3(128, 2, 2), 256, 0, stream>>>(wc1, x, nullptr, 192, bn3s, bn3b, vbuf, 192);
  // e = relu(bn2(w_e1 @ [x;k]))  (M=96, K=384)
  gemm_k<384, 0><<<dim3(128, 1, 2), 256, 0, stream>>>(we1, x, kbuf, 192, bn2s, bn2b, ebuf, 96);
  // wraw = w_e2 @ e + b_e2       (M=216, K=96)
  gemm_k<96, 2><<<dim3(128, 3, 2), 256, 0, stream>>>(we2, ebuf, nullptr, 96, nullptr, be2, wrbuf, 216);
  k3b_gnstats<<<dim3(8, 24, 2), 256, 0, stream>>>(wrbuf, gsums);
  k4_dynconv<<<dim3(16, 4, 16), 256, 0, stream>>>(wrbuf, vbuf, gsums, gns, gnb, bn4s, bn4b, x2);
  k5a_gap<<<dim3(384), 256, 0, stream>>>(x2, kbuf, gap);
  k5b_se<<<dim3(1), 256, 0, stream>>>(gap, wse1, bse1, bnses, bnseb, wse2, bse2, attnb);
  k6_combine<<<dim3(6144), 256, 0, stream>>>(kbuf, attnb, (float*)d_out);
}

// Round 3
// 383.628 us; speedup vs baseline: 1.7137x; 1.7137x over previous
//
#include <hip/hip_runtime.h>
#include <hip/hip_bf16.h>
#include <cstdint>

#define SP 16384

typedef __attribute__((ext_vector_type(8))) short bf16x8;
typedef __attribute__((ext_vector_type(4))) float f32x4;

__device__ inline unsigned short f2bf(float f) {
  unsigned u = __float_as_uint(f);
  unsigned r = (u + 0x7FFFu + ((u >> 16) & 1u)) >> 16;   // RNE
  return (unsigned short)r;
}

// ---------------- P1: pack wkey -> Apk bf16 [g][icch6][tapch7][oc48][t4][ic8] ----------
__global__ __launch_bounds__(256) void prep_w(const float* __restrict__ wkey,
                                              unsigned short* __restrict__ apk)
{
  int e = blockIdx.x * 256 + threadIdx.x;       // 258048 total
  int ic8 = e & 7;
  int t4 = (e >> 3) & 3;
  int rest = e >> 5;
  int oc = rest % 48;  int rest2 = rest / 48;
  int tapch = rest2 % 7; int rest3 = rest2 / 7;
  int icch = rest3 % 6; int g = rest3 / 6;
  int tap = tapch * 4 + t4;
  float v = 0.f;
  if (tap < 27)
    v = wkey[((size_t)(g * 48 + oc) * 48 + icch * 8 + ic8) * 27 + tap];
  apk[e] = f2bf(v);
}

// ---------------- P2: pack x -> xbf bf16 8ch-interleaved [b][cc24][n16384][8] ----------
__global__ __launch_bounds__(256) void prep_x(const float* __restrict__ x,
                                              unsigned short* __restrict__ xbf)
{
  int t = blockIdx.x * 256 + threadIdx.x;       // 786432 total
  int n = t & 16383;
  int v = t >> 14;                              // 0..47
  int cc = v % 24, b = v / 24;
  unsigned short o[8];
  #pragma unroll
  for (int i = 0; i < 8; ++i)
    o[i] = f2bf(x[(((size_t)b * 192 + cc * 8 + i) << 14) + n]);
  bf16x8 pk;
  #pragma unroll
  for (int i = 0; i < 8; ++i) pk[i] = (short)o[i];
  *(bf16x8*)&xbf[((size_t)t) << 3] = pk;
}

// ---------------- K1: grouped conv 3x3x3 via bf16 MFMA + BN1 + ReLU -> k ----------------
// tile = 2z x 4y x 32x (256 voxels); M=48 oc; K = 6 icch x 7 tapch x 32
__global__ __launch_bounds__(256) void k1_mfma(
    const unsigned short* __restrict__ xbf, const unsigned short* __restrict__ apk,
    const float* __restrict__ bn1s, const float* __restrict__ bn1b,
    float* __restrict__ kout)
{
  const int tile = blockIdx.x;                  // 64 = 8 z-tiles x 8 y-tiles
  const int g = blockIdx.y;
  const int b = blockIdx.z;
  const int z0 = (tile >> 3) * 2, y0 = (tile & 7) * 4;
  const int tid = threadIdx.x;
  const int lane = tid & 63, wid = tid >> 6;
  const int ln = lane & 15, lh = lane >> 4;

  __shared__ __align__(16) unsigned short xs[4 * 6 * 34 * 8];   // 6528 elems, 13 KB

  // per-lane tap -> LDS offset (elements) for each of 7 tap-chunks; tap 27 clamped (A=0)
  int offT[7];
  #pragma unroll
  for (int tc = 0; tc < 7; ++tc) {
    int tap = tc * 4 + lh; if (tap > 26) tap = 26;
    int dz = tap / 9, r = tap - dz * 9, dy = r / 3, dx = r - dy * 3;
    offT[tc] = dz * 1632 + dy * 272 + dx * 8;
  }
  const int zw = wid >> 1, yb = (wid & 1) * 2;  // wave's z (0/1) and y-pair base
  int bbase[4];
  #pragma unroll
  for (int f = 0; f < 4; ++f)
    bbase[f] = zw * 1632 + (yb + (f >> 1)) * 272 + ((f & 1) * 16 + ln) * 8;

  f32x4 acc[3][4];
  #pragma unroll
  for (int m = 0; m < 3; ++m)
    #pragma unroll
    for (int f = 0; f < 4; ++f) { f32x4 z4 = {0.f, 0.f, 0.f, 0.f}; acc[m][f] = z4; }

  const unsigned short* ag = apk + (size_t)g * 6 * 7 * 1536;

  for (int icch = 0; icch < 6; ++icch) {
    __syncthreads();
    const unsigned short* xsrc = xbf + (((size_t)(b * 24 + g * 6 + icch)) << 14) * 8;
    for (int e = tid; e < 816; e += 256) {       // 24 rows (4z' x 6y') x 34 x'
      int row = e / 34, xr = e - row * 34;
      int zz = row / 6, yy = row - zz * 6;
      int gz = z0 - 1 + zz, gy = y0 - 1 + yy, gx = xr - 1;
      bf16x8 v = {0, 0, 0, 0, 0, 0, 0, 0};
      if ((unsigned)gz < 16u && (unsigned)gy < 32u && (unsigned)gx < 32u)
        v = *(const bf16x8*)&xsrc[((gz << 10) + (gy << 5) + gx) * 8];
      *(bf16x8*)&xs[row * 272 + xr * 8] = v;
    }
    __syncthreads();
    const unsigned short* ab = ag + (size_t)icch * 7 * 1536;
    #pragma unroll
    for (int tc = 0; tc < 7; ++tc) {
      bf16x8 a0 = *(const bf16x8*)&ab[tc * 1536 + (0 * 16 + ln) * 32 + lh * 8];
      bf16x8 a1 = *(const bf16x8*)&ab[tc * 1536 + (1 * 16 + ln) * 32 + lh * 8];
      bf16x8 a2 = *(const bf16x8*)&ab[tc * 1536 + (2 * 16 + ln) * 32 + lh * 8];
      bf16x8 bb[4];
      #pragma unroll
      for (int f = 0; f < 4; ++f) bb[f] = *(const bf16x8*)&xs[bbase[f] + offT[tc]];
      #pragma unroll
      for (int f = 0; f < 4; ++f) {
        acc[0][f] = __builtin_amdgcn_mfma_f32_16x16x32_bf16(a0, bb[f], acc[0][f], 0, 0, 0);
        acc[1][f] = __builtin_amdgcn_mfma_f32_16x16x32_bf16(a1, bb[f], acc[1][f], 0, 0, 0);
        acc[2][f] = __builtin_amdgcn_mfma_f32_16x16x32_bf16(a2, bb[f], acc[2][f], 0, 0, 0);
      }
    }
  }
  // epilogue: D col = lane&15 (n), row = (lane>>4)*4 + r (oc)
  const int z = z0 + zw;
  #pragma unroll
  for (int mf = 0; mf < 3; ++mf) {
    #pragma unroll
    for (int r = 0; r < 4; ++r) {
      int oc = g * 48 + mf * 16 + lh * 4 + r;
      float sc = bn1s[oc], bi = bn1b[oc];
      #pragma unroll
      for (int f = 0; f < 4; ++f) {
        int y = y0 + yb + (f >> 1);
        int xq = (f & 1) * 16 + ln;
        float t = acc[mf][f][r] * sc + bi;
        kout[(((size_t)b * 192 + oc) << 14) + (z << 10) + (y << 5) + xq] = fmaxf(t, 0.f);
      }
    }
  }
}

// ---------------- generic fp32 GEMM: out[b][m][n] = epi(A[m][:] . In[b][:][n]) ----------
// EPI: 0 = relu(v*sc+bi), 1 = v*sc+bi, 2 = v+bi
template<int KTOT, int EPI>
__global__ __launch_bounds__(256) void gemm_k(
    const float* __restrict__ A,
    const float* __restrict__ src0, const float* __restrict__ src1, int c0,
    const float* __restrict__ sc, const float* __restrict__ bi,
    float* __restrict__ out, int M)
{
  const int n0 = blockIdx.x * 128;
  const int m_base = blockIdx.y * 96;
  const int b = blockIdx.z;
  const int tid = threadIdx.x;
  const int tn = tid & 15, tm = tid >> 4;
  __shared__ __align__(16) float Ws[16][96];
  __shared__ __align__(16) float Is[16][128];
  float acc[6][8] = {};
  for (int kc = 0; kc < KTOT; kc += 16) {
    __syncthreads();
    #pragma unroll
    for (int i = 0; i < 2; ++i) {
      int idx = tid + i * 256;
      int r = idx >> 5, c4 = idx & 31;
      int ch = kc + r;
      const float* s = (ch < c0) ? src0 + (((size_t)b * c0 + ch) << 14)
                                 : src1 + (((size_t)(b * 192) + (ch - c0)) << 14);
      *(float4*)&Is[r][c4 * 4] = *(const float4*)(s + n0 + c4 * 4);
    }
    for (int idx = tid; idx < 384; idx += 256) {
      int m = idx >> 2, kq = idx & 3;
      int gm = m_base + m;
      float4 w = {0.f, 0.f, 0.f, 0.f};
      if (gm < M) w = *(const float4*)(A + (size_t)gm * KTOT + kc + kq * 4);
      Ws[kq * 4 + 0][m] = w.x;
      Ws[kq * 4 + 1][m] = w.y;
      Ws[kq * 4 + 2][m] = w.z;
      Ws[kq * 4 + 3][m] = w.w;
    }
    __syncthreads();
    #pragma unroll
    for (int kk = 0; kk < 16; ++kk) {
      float av[6];
      #pragma unroll
      for (int i = 0; i < 6; ++i) av[i] = Ws[kk][tm * 6 + i];
      float4 b0 = *(const float4*)&Is[kk][tn * 8];
      float4 b1 = *(const float4*)&Is[kk][tn * 8 + 4];
      float bv[8] = {b0.x, b0.y, b0.z, b0.w, b1.x, b1.y, b1.z, b1.w};
      #pragma unroll
      for (int i = 0; i < 6; ++i)
        #pragma unroll
        for (int j = 0; j < 8; ++j)
          acc[i][j] += av[i] * bv[j];
    }
  }
  #pragma unroll
  for (int i = 0; i < 6; ++i) {
    int gm = m_base + tm * 6 + i;
    if (gm >= M) continue;
    float scv = (EPI == 2) ? 1.f : sc[gm];
    float biv = bi[gm];
    float r[8];
    #pragma unroll
    for (int j = 0; j < 8; ++j) {
      float t = acc[i][j] * scv + biv;
      r[j] = (EPI == 0) ? fmaxf(t, 0.f) : t;
    }
    float* op = out + (((size_t)b * M + gm) << 14) + n0 + tn * 8;
    float4 r0 = {r[0], r[1], r[2], r[3]}, r1 = {r[4], r[5], r[6], r[7]};
    *(float4*)op = r0;
    *(float4*)(op + 4) = r1;
  }
}

// ---------------- K3b: GroupNorm stats (sum, sumsq) per (b, group of 9 ch) -------------
__global__ __launch_bounds__(256) void k3b_gnstats(const float* __restrict__ wraw,
                                                   float* __restrict__ gsums)
{
  const int chunk = blockIdx.x, g = blockIdx.y, b = blockIdx.z;
  const float4* p = (const float4*)(wraw + (((size_t)b * 216 + g * 9) << 14));
  float s1 = 0.f, s2 = 0.f;
  const int base = chunk * 4608 + threadIdx.x;
  #pragma unroll 4
  for (int i = 0; i < 18; ++i) {
    float4 v = p[base + i * 256];
    s1 += v.x + v.y + v.z + v.w;
    s2 += v.x * v.x + v.y * v.y + v.z * v.z + v.w * v.w;
  }
  #pragma unroll
  for (int o = 32; o > 0; o >>= 1) { s1 += __shfl_down(s1, o); s2 += __shfl_down(s2, o); }
  __shared__ float ps[4][2];
  int lane = threadIdx.x & 63, w = threadIdx.x >> 6;
  if (lane == 0) { ps[w][0] = s1; ps[w][1] = s2; }
  __syncthreads();
  if (threadIdx.x == 0) {
    float t1 = ps[0][0] + ps[1][0] + ps[2][0] + ps[3][0];
    float t2 = ps[0][1] + ps[1][1] + ps[2][1] + ps[3][1];
    atomicAdd(&gsums[(b * 24 + g) * 2 + 0], t1);
    atomicAdd(&gsums[(b * 24 + g) * 2 + 1], t2);
  }
}

// ---------------- K4: dynamic 3x3x3 conv + BN4 + SiLU -> x2 (stored in d_out) ----------
__global__ __launch_bounds__(256) void k4_dynconv(
    const float* __restrict__ wraw, const float* __restrict__ vbuf,
    const float* __restrict__ gsums,
    const float* __restrict__ gns, const float* __restrict__ gnb,
    const float* __restrict__ bn4s, const float* __restrict__ bn4b,
    float* __restrict__ x2)
{
  const int tile = blockIdx.x;
  const int z0 = (tile >> 2) * 4, y0 = (tile & 3) * 8;
  const int cs = blockIdx.y;
  const int b = blockIdx.z >> 3, gw = blockIdx.z & 7;
  const int tid = threadIdx.x;
  const int tx = (tid & 7) * 4, ty = (tid >> 3) & 7, tz = tid >> 6;

  __shared__ __align__(16) float vs[6][6][10][35];
  __shared__ __align__(16) float wls[3][1024];

  float mu[3], rs[3];
  #pragma unroll
  for (int j = 0; j < 3; ++j) {
    int gr = gw * 3 + j;
    float m1 = gsums[(b * 24 + gr) * 2 + 0] * (1.f / 147456.f);
    float m2 = gsums[(b * 24 + gr) * 2 + 1] * (1.f / 147456.f);
    mu[j] = m1;
    rs[j] = rsqrtf(m2 - m1 * m1 + 1e-5f);
  }
  const int c0 = gw * 24 + cs * 6;
  for (int e = tid; e < 6 * 2040; e += 256) {
    int cc = e / 2040; int r = e - cc * 2040;
    int zz = r / 340;  int r2 = r - zz * 340;
    int yy = r2 / 34;  int xx = r2 - yy * 34;
    int gz = z0 - 1 + zz, gy = y0 - 1 + yy, gx = xx - 1;
    float val = 0.f;
    if (gz >= 0 && gz < 16 && gy >= 0 && gy < 32 && gx >= 0 && gx < 32)
      val = vbuf[(((size_t)b * 192 + c0 + cc) << 14) + (gz << 10) + (gy << 5) + gx];
    vs[cc][zz][yy][xx] = val;
  }
  float acc[6][4] = {};
  for (int chnk = 0; chnk < 9; ++chnk) {             // (dz,dy)
    const int dz = chnk / 3, dy = chnk - dz * 3;
    __syncthreads();                                 // covers vs stage (1st) + wls reuse
    #pragma unroll
    for (int i = 0; i < 3; ++i) {                    // stage 3 normalized weight planes
      int e4 = tid + i * 256;
      int idxi = e4 >> 8, s4 = e4 & 255;
      int zz = s4 >> 6, rem = s4 & 63, yy = rem >> 3, x4 = rem & 7;
      int cw = gw * 27 + chnk * 3 + idxi;
      float scw = rs[dz] * gns[cw];
      float shw = gnb[cw] - mu[dz] * scw;
      float4 wv = *(const float4*)&wraw[(((size_t)b * 216 + cw) << 14) +
                                        ((z0 + zz) << 10) + ((y0 + yy) << 5) + (x4 << 2)];
      float4 o4;
      o4.x = wv.x * scw + shw; o4.y = wv.y * scw + shw;
      o4.z = wv.z * scw + shw; o4.w = wv.w * scw + shw;
      int row = zz * 8 + yy;
      ((float4*)&wls[idxi][0])[(row << 3) | (x4 ^ (row & 7))] = o4;   // XOR swizzle
    }
    __syncthreads();
    float xv[6][6];
    #pragma unroll
    for (int cc = 0; cc < 6; ++cc)
      #pragma unroll
      for (int j = 0; j < 6; ++j) xv[cc][j] = vs[cc][tz + dz][ty + dy][tx + j];
    const int row = tz * 8 + ty;
    #pragma unroll
    for (int dxi = 0; dxi < 3; ++dxi) {
      float4 wv = ((const float4*)&wls[dxi][0])[(row << 3) | ((tx >> 2) ^ (row & 7))];
      float w4[4] = {wv.x, wv.y, wv.z, wv.w};
      #pragma unroll
      for (int cc = 0; cc < 6; ++cc)
        #pragma unroll
        for (int xi = 0; xi < 4; ++xi)
          acc[cc][xi] += w4[xi] * xv[cc][dxi + xi];
    }
  }
  #pragma unroll
  for (int cc = 0; cc < 6; ++cc) {
    int c = c0 + cc;
    float scv = bn4s[c], bb = bn4b[c];
    float4 r;
    float t;
    t = acc[cc][0] * scv + bb; r.x = t / (1.f + expf(-t));
    t = acc[cc][1] * scv + bb; r.y = t / (1.f + expf(-t));
    t = acc[cc][2] * scv + bb; r.z = t / (1.f + expf(-t));
    t = acc[cc][3] * scv + bb; r.w = t / (1.f + expf(-t));
    *(float4*)&x2[(((size_t)b * 192 + c) << 14) + ((z0 + tz) << 10) + ((y0 + ty) << 5) + tx] = r;
  }
}

// ---------------- K5a: gap[b][c] = mean_s(x2 + k) ----------------
__global__ __launch_bounds__(256) void k5a_gap(const float* __restrict__ x2,
                                               const float* __restrict__ k,
                                               float* __restrict__ gap)
{
  const int bc = blockIdx.x;
  const float4* p1 = (const float4*)(x2 + ((size_t)bc << 14));
  const float4* p2 = (const float4*)(k + ((size_t)bc << 14));
  float s = 0.f;
  for (int i = threadIdx.x; i < 4096; i += 256) {
    float4 a = p1[i], b2 = p2[i];
    s += (a.x + b2.x) + (a.y + b2.y) + (a.z + b2.z) + (a.w + b2.w);
  }
  #pragma unroll
  for (int o = 32; o > 0; o >>= 1) s += __shfl_down(s, o);
  __shared__ float ps[4];
  if ((threadIdx.x & 63) == 0) ps[threadIdx.x >> 6] = s;
  __syncthreads();
  if (threadIdx.x == 0) gap[bc] = (ps[0] + ps[1] + ps[2] + ps[3]) * (1.f / 16384.f);
}

// ---------------- K5b: SE head -> per-channel softmax pair ----------------
__global__ __launch_bounds__(256) void k5b_se(
    const float* __restrict__ gap,
    const float* __restrict__ wse1, const float* __restrict__ bse1,
    const float* __restrict__ bnses, const float* __restrict__ bnseb,
    const float* __restrict__ wse2, const float* __restrict__ bse2,
    float* __restrict__ attnb)
{
  __shared__ float g[384];
  __shared__ float h[192];
  __shared__ float at[768];
  const int tid = threadIdx.x;
  for (int t = tid; t < 384; t += 256) g[t] = gap[t];
  __syncthreads();
  if (tid < 192) {
    int b = tid / 96, o = tid - b * 96;
    float s = 0.f;
    for (int i = 0; i < 192; ++i) s += wse1[o * 192 + i] * g[b * 192 + i];
    s = (s + bse1[o]) * bnses[o] + bnseb[o];
    h[tid] = fmaxf(s, 0.f);
  }
  __syncthreads();
  for (int t = tid; t < 768; t += 256) {
    int b = t / 384, o = t - b * 384;
    float s = 0.f;
    for (int i = 0; i < 96; ++i) s += wse2[o * 96 + i] * h[b * 96 + i];
    at[t] = s + bse2[o];
  }
  __syncthreads();
  for (int t = tid; t < 384; t += 256) {
    int b = t / 192, c = t - b * 192;
    float a0 = at[b * 384 + 2 * c], a1 = at[b * 384 + 2 * c + 1];
    float m = fmaxf(a0, a1);
    float e0 = expf(a0 - m), e1 = expf(a1 - m);
    float inv = 1.f / (e0 + e1);
    attnb[t * 2 + 0] = e0 * inv;
    attnb[t * 2 + 1] = e1 * inv;
  }
}

// ---------------- K6: out = x2*p0 + k*p1 (in place: io holds x2) ----------------
__global__ __launch_bounds__(256) void k6_combine(const float* __restrict__ k,
                                                  const float* __restrict__ attnb,
                                                  float* io)
{
  const int i4 = blockIdx.x * 256 + threadIdx.x;
  const int bc = i4 >> 12;
  float p0 = attnb[bc * 2 + 0], p1 = attnb[bc * 2 + 1];
  float4 a = ((const float4*)io)[i4];
  float4 kk = ((const float4*)k)[i4];
  float4 r;
  r.x = a.x * p0 + kk.x * p1;
  r.y = a.y * p0 + kk.y * p1;
  r.z = a.z * p0 + kk.z * p1;
  r.w = a.w * p0 + kk.w * p1;
  ((float4*)io)[i4] = r;
}

extern "C" void kernel_launch(void* const* d_in, const int* in_sizes, int n_in,
                              void* d_out, int out_size, void* d_ws, size_t ws_size,
                              hipStream_t stream) {
  const float* x     = (const float*)d_in[0];
  const float* wkey  = (const float*)d_in[1];
  const float* bn1s  = (const float*)d_in[2];
  const float* bn1b  = (const float*)d_in[3];
  const float* we1   = (const float*)d_in[4];
  const float* bn2s  = (const float*)d_in[5];
  const float* bn2b  = (const float*)d_in[6];
  const float* we2   = (const float*)d_in[7];
  const float* be2   = (const float*)d_in[8];
  const float* gns   = (const float*)d_in[9];
  const float* gnb   = (const float*)d_in[10];
  const float* wc1   = (const float*)d_in[11];
  const float* bn3s  = (const float*)d_in[12];
  const float* bn3b  = (const float*)d_in[13];
  const float* bn4s  = (const float*)d_in[14];
  const float* bn4b  = (const float*)d_in[15];
  const float* wse1  = (const float*)d_in[16];
  const float* bse1  = (const float*)d_in[17];
  const float* bnses = (const float*)d_in[18];
  const float* bnseb = (const float*)d_in[19];
  const float* wse2  = (const float*)d_in[20];
  const float* bse2  = (const float*)d_in[21];

  float* ws    = (float*)d_ws;
  float* kbuf  = ws + 0;          // 2*192*SP = 6291456
  float* ebuf  = ws + 6291456;    // 2* 96*SP = 3145728
  float* wrbuf = ws + 9437184;    // 2*216*SP = 7077888
  float* vbuf  = ws + 16515072;   // 2*192*SP = 6291456
  float* gsums = ws + 22806528;   // 96
  float* gap   = ws + 22806624;   // 384
  float* attnb = ws + 22807008;   // 768
  float* x2    = (float*)d_out;   // x2 lives in d_out; K6 finishes in place

  // xbf (6291456 bf16 = 3145728 fl) + Apk (258048 bf16 = 129024 fl) alias wrbuf:
  // both are dead before gemm_w writes wrbuf.
  unsigned short* xbf = (unsigned short*)(ws + 9437184);
  unsigned short* apk = (unsigned short*)(ws + 9437184 + 3145728);

  hipMemsetAsync(gsums, 0, 96 * sizeof(float), stream);

  prep_w<<<dim3(1008), 256, 0, stream>>>(wkey, apk);
  prep_x<<<dim3(3072), 256, 0, stream>>>(x, xbf);
  k1_mfma<<<dim3(64, 4, 2), 256, 0, stream>>>(xbf, apk, bn1s, bn1b, kbuf);
  // v = bn3(w_c1 @ x)            (M=192, K=192, no relu)
  gemm_k<192, 1><<<dim3(128, 2, 2), 256, 0, stream>>>(wc1, x, nullptr, 192, bn3s, bn3b, vbuf, 192);
  // e = relu(bn2(w_e1 @ [x;k]))  (M=96, K=384)
  gemm_k<384, 0><<<dim3(128, 1, 2), 256, 0, stream>>>(we1, x, kbuf, 192, bn2s, bn2b, ebuf, 96);
  // wraw = w_e2 @ e + b_e2       (M=216, K=96)  — overwrites xbf/apk region (dead)
  gemm_k<96, 2><<<dim3(128, 3, 2), 256, 0, stream>>>(we2, ebuf, nullptr, 96, nullptr, be2, wrbuf, 216);
  k3b_gnstats<<<dim3(8, 24, 2), 256, 0, stream>>>(wrbuf, gsums);
  k4_dynconv<<<dim3(16, 4, 16), 256, 0, stream>>>(wrbuf, vbuf, gsums, gns, gnb, bn4s, bn4b, x2);
  k5a_gap<<<dim3(384), 256, 0, stream>>>(x2, kbuf, gap);
  k5b_se<<<dim3(1), 256, 0, stream>>>(gap, wse1, bse1, bnses, bnseb, wse2, bse2, attnb);
  k6_combine<<<dim3(6144), 256, 0, stream>>>(kbuf, attnb, (float*)d_out);
}

// Round 7
// 314.753 us; speedup vs baseline: 2.0887x; 1.2188x over previous
//
#include <hip/hip_runtime.h>
#include <hip/hip_bf16.h>
#include <cstdint>

#define SP 16384

typedef __attribute__((ext_vector_type(8))) short bf16x8;
typedef __attribute__((ext_vector_type(4))) short bf16x4;
typedef __attribute__((ext_vector_type(4))) float f32x4;

__device__ inline unsigned short f2bf(float f) {
  unsigned u = __float_as_uint(f);
  unsigned r = (u + 0x7FFFu + ((u >> 16) & 1u)) >> 16;   // RNE
  return (unsigned short)r;
}
__device__ inline float bf2f(unsigned short h) {
  return __uint_as_float(((unsigned)h) << 16);
}

// ---------------- P1: pack wkey -> apk1 bf16 [g][icch6][tapch7][oc48][t4][ic8] ----------
__global__ __launch_bounds__(256) void prep_w(const float* __restrict__ wkey,
                                              unsigned short* __restrict__ apk)
{
  int e = blockIdx.x * 256 + threadIdx.x;       // 258048 total
  int ic8 = e & 7;
  int t4 = (e >> 3) & 3;
  int rest = e >> 5;
  int oc = rest % 48;  int rest2 = rest / 48;
  int tapch = rest2 % 7; int rest3 = rest2 / 7;
  int icch = rest3 % 6; int g = rest3 / 6;
  int tap = tapch * 4 + t4;
  float v = 0.f;
  if (tap < 27)
    v = wkey[((size_t)(g * 48 + oc) * 48 + icch * 8 + ic8) * 27 + tap];
  apk[e] = f2bf(v);
}

// ---------------- P2: pack x -> actbf cc 0..23 of [b][cc48][n16384][8] ----------
__global__ __launch_bounds__(256) void prep_x(const float* __restrict__ x,
                                              unsigned short* __restrict__ actbf)
{
  int t = blockIdx.x * 256 + threadIdx.x;       // 786432 total
  int n = t & 16383;
  int v = t >> 14;                              // 0..47
  int cc = v % 24, b = v / 24;
  bf16x8 pk;
  #pragma unroll
  for (int i = 0; i < 8; ++i)
    pk[i] = (short)f2bf(x[(((size_t)b * 192 + cc * 8 + i) << 14) + n]);
  *(bf16x8*)&actbf[((size_t)(b * 48 + cc) * 16384 + n) * 8] = pk;
}

// ---------------- P3: generic A-pack: src[M][K] fp32 -> [mf][kc][r16][lh4][j8] bf16 ------
__global__ __launch_bounds__(256) void pack_a(const float* __restrict__ src,
                                              unsigned short* __restrict__ dst,
                                              int M, int K)
{
  int e = blockIdx.x * 256 + threadIdx.x;       // exact grid
  int j = e & 7, lh = (e >> 3) & 3, r = (e >> 5) & 15;
  int rest = e >> 9;
  int KCH = K >> 5;
  int kc = rest % KCH, mf = rest / KCH;
  int m = mf * 16 + r, k = kc * 32 + lh * 8 + j;
  dst[e] = (m < M) ? f2bf(src[(size_t)m * K + k]) : (unsigned short)0;
}

// ---------------- K1: grouped conv 3x3x3 via bf16 MFMA + BN1 + ReLU -> k (fp32 + bf16) --
__global__ __launch_bounds__(256) void k1_mfma(
    const unsigned short* __restrict__ actbf_in, const unsigned short* __restrict__ apk,
    const float* __restrict__ bn1s, const float* __restrict__ bn1b,
    float* __restrict__ kout, unsigned short* __restrict__ actbf_out)
{
  const int tile = blockIdx.x;                  // 64 = 8 z-tiles x 8 y-tiles
  const int g = blockIdx.y;
  const int b = blockIdx.z;
  const int z0 = (tile >> 3) * 2, y0 = (tile & 7) * 4;
  const int tid = threadIdx.x;
  const int lane = tid & 63, wid = tid >> 6;
  const int ln = lane & 15, lh = lane >> 4;

  __shared__ __align__(16) unsigned short xs[4 * 6 * 34 * 8];   // 13 KB

  int offT[7];
  #pragma unroll
  for (int tc = 0; tc < 7; ++tc) {
    int tap = tc * 4 + lh; if (tap > 26) tap = 26;
    int dz = tap / 9, r = tap - dz * 9, dy = r / 3, dx = r - dy * 3;
    offT[tc] = dz * 1632 + dy * 272 + dx * 8;
  }
  const int zw = wid >> 1, yb = (wid & 1) * 2;
  int bbase[4];
  #pragma unroll
  for (int f = 0; f < 4; ++f)
    bbase[f] = zw * 1632 + (yb + (f >> 1)) * 272 + ((f & 1) * 16 + ln) * 8;

  f32x4 acc[3][4];
  #pragma unroll
  for (int m = 0; m < 3; ++m)
    #pragma unroll
    for (int f = 0; f < 4; ++f) { f32x4 z4 = {0.f, 0.f, 0.f, 0.f}; acc[m][f] = z4; }

  const unsigned short* ag = apk + (size_t)g * 6 * 7 * 1536;

  for (int icch = 0; icch < 6; ++icch) {
    __syncthreads();
    const unsigned short* xsrc = actbf_in + ((size_t)(b * 48 + g * 6 + icch) * 16384) * 8;
    for (int e = tid; e < 816; e += 256) {
      int row = e / 34, xr = e - row * 34;
      int zz = row / 6, yy = row - zz * 6;
      int gz = z0 - 1 + zz, gy = y0 - 1 + yy, gx = xr - 1;
      bf16x8 v = {0, 0, 0, 0, 0, 0, 0, 0};
      if ((unsigned)gz < 16u && (unsigned)gy < 32u && (unsigned)gx < 32u)
        v = *(const bf16x8*)&xsrc[((gz << 10) + (gy << 5) + gx) * 8];
      *(bf16x8*)&xs[row * 272 + xr * 8] = v;
    }
    __syncthreads();
    const unsigned short* ab = ag + (size_t)icch * 7 * 1536;
    #pragma unroll
    for (int tc = 0; tc < 7; ++tc) {
      bf16x8 a0 = *(const bf16x8*)&ab[tc * 1536 + (0 * 16 + ln) * 32 + lh * 8];
      bf16x8 a1 = *(const bf16x8*)&ab[tc * 1536 + (1 * 16 + ln) * 32 + lh * 8];
      bf16x8 a2 = *(const bf16x8*)&ab[tc * 1536 + (2 * 16 + ln) * 32 + lh * 8];
      bf16x8 bb[4];
      #pragma unroll
      for (int f = 0; f < 4; ++f) bb[f] = *(const bf16x8*)&xs[bbase[f] + offT[tc]];
      #pragma unroll
      for (int f = 0; f < 4; ++f) {
        acc[0][f] = __builtin_amdgcn_mfma_f32_16x16x32_bf16(a0, bb[f], acc[0][f], 0, 0, 0);
        acc[1][f] = __builtin_amdgcn_mfma_f32_16x16x32_bf16(a1, bb[f], acc[1][f], 0, 0, 0);
        acc[2][f] = __builtin_amdgcn_mfma_f32_16x16x32_bf16(a2, bb[f], acc[2][f], 0, 0, 0);
      }
    }
  }
  const int z = z0 + zw;
  #pragma unroll
  for (int mf = 0; mf < 3; ++mf) {
    #pragma unroll
    for (int f = 0; f < 4; ++f) {
      const int y = y0 + yb + (f >> 1);
      const int xq = (f & 1) * 16 + ln;
      const int n = (z << 10) + (y << 5) + xq;
      unsigned short h4[4];
      #pragma unroll
      for (int r = 0; r < 4; ++r) {
        int oc = g * 48 + mf * 16 + lh * 4 + r;
        float t = fmaxf(acc[mf][f][r] * bn1s[oc] + bn1b[oc], 0.f);
        kout[(((size_t)b * 192 + oc) << 14) + n] = t;
        h4[r] = f2bf(t);
      }
      int cc = 24 + g * 6 + mf * 2 + (lh >> 1);
      bf16x4 hv = {(short)h4[0], (short)h4[1], (short)h4[2], (short)h4[3]};
      *(bf16x4*)&actbf_out[((size_t)(b * 48 + cc) * 16384 + n) * 8 + (lh & 1) * 4] = hv;
    }
  }
}

// ---------------- K2: LDS-free bf16 MFMA 1x1 GEMM ----------------
// A: apk [mf][kc][r16][lh4][j8]; B: bact [b][BPL][16384][8] (cc = kc*4+lh)
// EPI 0: relu(v*sc+bi) -> bf16 hi/lo interleaved [b][12][n][8] (+lo at +3145728)
// EPI 1: v*sc+bi -> fp32 planar [b][Mfull][n]
// EPI 2: v+bi    -> fp32 planar, guard c<Mfull
// SPLITB: second B copy (lo) at +3145728 shorts, accumulated in.
template<int KCH, int MT, int EPI, int SPLITB, int BPL>
__global__ __launch_bounds__(256) void gemm_mfma(
    const unsigned short* __restrict__ apk,
    const unsigned short* __restrict__ bact,
    const float* __restrict__ sc, const float* __restrict__ bi,
    float* __restrict__ outf, unsigned short* __restrict__ outbf,
    int Mfull)
{
  const int b = blockIdx.z;
  const int tid = threadIdx.x;
  const int lane = tid & 63, wid = tid >> 6;
  const int ln = lane & 15, lh = lane >> 4;
  const int n = blockIdx.x * 64 + wid * 16 + ln;

  f32x4 acc[MT];
  #pragma unroll
  for (int m = 0; m < MT; ++m) { f32x4 z = {0.f, 0.f, 0.f, 0.f}; acc[m] = z; }

  const unsigned short* bb = bact + ((size_t)(b * BPL + lh) * 16384 + n) * 8;
  #pragma unroll
  for (int kc = 0; kc < KCH; ++kc) {
    bf16x8 bfr = *(const bf16x8*)(bb + (size_t)kc * 4 * 131072);
    bf16x8 bfr2;
    if (SPLITB) bfr2 = *(const bf16x8*)(bb + 3145728 + (size_t)kc * 4 * 131072);
    #pragma unroll
    for (int m = 0; m < MT; ++m) {
      bf16x8 afr = *(const bf16x8*)&apk[(((m * KCH + kc) * 16 + ln) * 4 + lh) * 8];
      acc[m] = __builtin_amdgcn_mfma_f32_16x16x32_bf16(afr, bfr, acc[m], 0, 0, 0);
      if (SPLITB)
        acc[m] = __builtin_amdgcn_mfma_f32_16x16x32_bf16(afr, bfr2, acc[m], 0, 0, 0);
    }
  }
  #pragma unroll
  for (int m = 0; m < MT; ++m) {
    int c0 = m * 16 + lh * 4;
    if (EPI == 0) {
      unsigned short h[4], l[4];
      #pragma unroll
      for (int r = 0; r < 4; ++r) {
        int c = c0 + r;
        float t = fmaxf(acc[m][r] * sc[c] + bi[c], 0.f);
        h[r] = f2bf(t);
        l[r] = f2bf(t - bf2f(h[r]));
      }
      int cc = m * 2 + (lh >> 1);
      size_t o = ((size_t)(b * 12 + cc) * 16384 + n) * 8 + (lh & 1) * 4;
      bf16x4 hv = {(short)h[0], (short)h[1], (short)h[2], (short)h[3]};
      bf16x4 lv = {(short)l[0], (short)l[1], (short)l[2], (short)l[3]};
      *(bf16x4*)&outbf[o] = hv;
      *(bf16x4*)&outbf[o + 3145728] = lv;
    } else {
      #pragma unroll
      for (int r = 0; r < 4; ++r) {
        int c = c0 + r;
        if (EPI == 2 && c >= Mfull) continue;
        float t = (EPI == 1) ? (acc[m][r] * sc[c] + bi[c]) : (acc[m][r] + bi[c]);
        outf[(((size_t)b * Mfull + c) << 14) + n] = t;
      }
    }
  }
}

// ---------------- K3b: GroupNorm stats (sum, sumsq) per (b, group of 9 ch) -------------
__global__ __launch_bounds__(256) void k3b_gnstats(const float* __restrict__ wraw,
                                                   float* __restrict__ gsums)
{
  const int chunk = blockIdx.x, g = blockIdx.y, b = blockIdx.z;
  const float4* p = (const float4*)(wraw + (((size_t)b * 216 + g * 9) << 14));
  float s1 = 0.f, s2 = 0.f;
  const int base = chunk * 4608 + threadIdx.x;
  #pragma unroll 4
  for (int i = 0; i < 18; ++i) {
    float4 v = p[base + i * 256];
    s1 += v.x + v.y + v.z + v.w;
    s2 += v.x * v.x + v.y * v.y + v.z * v.z + v.w * v.w;
  }
  #pragma unroll
  for (int o = 32; o > 0; o >>= 1) { s1 += __shfl_down(s1, o); s2 += __shfl_down(s2, o); }
  __shared__ float ps[4][2];
  int lane = threadIdx.x & 63, w = threadIdx.x >> 6;
  if (lane == 0) { ps[w][0] = s1; ps[w][1] = s2; }
  __syncthreads();
  if (threadIdx.x == 0) {
    float t1 = ps[0][0] + ps[1][0] + ps[2][0] + ps[3][0];
    float t2 = ps[0][1] + ps[1][1] + ps[2][1] + ps[3][1];
    atomicAdd(&gsums[(b * 24 + g) * 2 + 0], t1);
    atomicAdd(&gsums[(b * 24 + g) * 2 + 1], t2);
  }
}

// ---------------- K4: dynamic 3x3x3 conv + BN4 + SiLU -> x2 (stored in d_out) ----------
__global__ __launch_bounds__(256) void k4_dynconv(
    const float* __restrict__ wraw, const float* __restrict__ vbuf,
    const float* __restrict__ gsums,
    const float* __restrict__ gns, const float* __restrict__ gnb,
    const float* __restrict__ bn4s, const float* __restrict__ bn4b,
    float* __restrict__ x2)
{
  const int tile = blockIdx.x;
  const int z0 = (tile >> 2) * 4, y0 = (tile & 3) * 8;
  const int cs = blockIdx.y;
  const int b = blockIdx.z >> 3, gw = blockIdx.z & 7;
  const int tid = threadIdx.x;
  const int tx = (tid & 7) * 4, ty = (tid >> 3) & 7, tz = tid >> 6;

  __shared__ __align__(16) float vs[6][6][10][35];
  __shared__ __align__(16) float wls[3][1024];

  float mu[3], rs[3];
  #pragma unroll
  for (int j = 0; j < 3; ++j) {
    int gr = gw * 3 + j;
    float m1 = gsums[(b * 24 + gr) * 2 + 0] * (1.f / 147456.f);
    float m2 = gsums[(b * 24 + gr) * 2 + 1] * (1.f / 147456.f);
    mu[j] = m1;
    rs[j] = rsqrtf(m2 - m1 * m1 + 1e-5f);
  }
  const int c0 = gw * 24 + cs * 6;
  for (int e = tid; e < 6 * 2040; e += 256) {
    int cc = e / 2040; int r = e - cc * 2040;
    int zz = r / 340;  int r2 = r - zz * 340;
    int yy = r2 / 34;  int xx = r2 - yy * 34;
    int gz = z0 - 1 + zz, gy = y0 - 1 + yy, gx = xx - 1;
    float val = 0.f;
    if (gz >= 0 && gz < 16 && gy >= 0 && gy < 32 && gx >= 0 && gx < 32)
      val = vbuf[(((size_t)b * 192 + c0 + cc) << 14) + (gz << 10) + (gy << 5) + gx];
    vs[cc][zz][yy][xx] = val;
  }
  float acc[6][4] = {};
  for (int chnk = 0; chnk < 9; ++chnk) {             // (dz,dy)
    const int dz = chnk / 3, dy = chnk - dz * 3;
    __syncthreads();
    #pragma unroll
    for (int i = 0; i < 3; ++i) {
      int e4 = tid + i * 256;
      int idxi = e4 >> 8, s4 = e4 & 255;
      int zz = s4 >> 6, rem = s4 & 63, yy = rem >> 3, x4 = rem & 7;
      int cw = gw * 27 + chnk * 3 + idxi;
      float scw = rs[dz] * gns[cw];
      float shw = gnb[cw] - mu[dz] * scw;
      float4 wv = *(const float4*)&wraw[(((size_t)b * 216 + cw) << 14) +
                                        ((z0 + zz) << 10) + ((y0 + yy) << 5) + (x4 << 2)];
      float4 o4;
      o4.x = wv.x * scw + shw; o4.y = wv.y * scw + shw;
      o4.z = wv.z * scw + shw; o4.w = wv.w * scw + shw;
      int row = zz * 8 + yy;
      ((float4*)&wls[idxi][0])[(row << 3) | (x4 ^ (row & 7))] = o4;
    }
    __syncthreads();
    float xv[6][6];
    #pragma unroll
    for (int cc = 0; cc < 6; ++cc)
      #pragma unroll
      for (int j = 0; j < 6; ++j) xv[cc][j] = vs[cc][tz + dz][ty + dy][tx + j];
    const int row = tz * 8 + ty;
    #pragma unroll
    for (int dxi = 0; dxi < 3; ++dxi) {
      float4 wv = ((const float4*)&wls[dxi][0])[(row << 3) | ((tx >> 2) ^ (row & 7))];
      float w4[4] = {wv.x, wv.y, wv.z, wv.w};
      #pragma unroll
      for (int cc = 0; cc < 6; ++cc)
        #pragma unroll
        for (int xi = 0; xi < 4; ++xi)
          acc[cc][xi] += w4[xi] * xv[cc][dxi + xi];
    }
  }
  #pragma unroll
  for (int cc = 0; cc < 6; ++cc) {
    int c = c0 + cc;
    float scv = bn4s[c], bb = bn4b[c];
    float4 r;
    float t;
    t = acc[cc][0] * scv + bb; r.x = t / (1.f + expf(-t));
    t = acc[cc][1] * scv + bb; r.y = t / (1.f + expf(-t));
    t = acc[cc][2] * scv + bb; r.z = t / (1.f + expf(-t));
    t = acc[cc][3] * scv + bb; r.w = t / (1.f + expf(-t));
    *(float4*)&x2[(((size_t)b * 192 + c) << 14) + ((z0 + tz) << 10) + ((y0 + ty) << 5) + tx] = r;
  }
}

// ---------------- K5a: gap[b][c] = mean_s(x2 + k) ----------------
__global__ __launch_bounds__(256) void k5a_gap(const float* __restrict__ x2,
                                               const float* __restrict__ k,
                                               float* __restrict__ gap)
{
  const int bc = blockIdx.x;
  const float4* p1 = (const float4*)(x2 + ((size_t)bc << 14));
  const float4* p2 = (const float4*)(k + ((size_t)bc << 14));
  float s = 0.f;
  for (int i = threadIdx.x; i < 4096; i += 256) {
    float4 a = p1[i], b2 = p2[i];
    s += (a.x + b2.x) + (a.y + b2.y) + (a.z + b2.z) + (a.w + b2.w);
  }
  #pragma unroll
  for (int o = 32; o > 0; o >>= 1) s += __shfl_down(s, o);
  __shared__ float ps[4];
  if ((threadIdx.x & 63) == 0) ps[threadIdx.x >> 6] = s;
  __syncthreads();
  if (threadIdx.x == 0) gap[bc] = (ps[0] + ps[1] + ps[2] + ps[3]) * (1.f / 16384.f);
}

// ---------------- K5b: SE head -> per-channel softmax pair ----------------
__global__ __launch_bounds__(256) void k5b_se(
    const float* __restrict__ gap,
    const float* __restrict__ wse1, const float* __restrict__ bse1,
    const float* __restrict__ bnses, const float* __restrict__ bnseb,
    const float* __restrict__ wse2, const float* __restrict__ bse2,
    float* __restrict__ attnb)
{
  __shared__ float g[384];
  __shared__ float h[192];
  __shared__ float at[768];
  const int tid = threadIdx.x;
  for (int t = tid; t < 384; t += 256) g[t] = gap[t];
  __syncthreads();
  if (tid < 192) {
    int b = tid / 96, o = tid - b * 96;
    float s = 0.f;
    for (int i = 0; i < 192; ++i) s += wse1[o * 192 + i] * g[b * 192 + i];
    s = (s + bse1[o]) * bnses[o] + bnseb[o];
    h[tid] = fmaxf(s, 0.f);
  }
  __syncthreads();
  for (int t = tid; t < 768; t += 256) {
    int b = t / 384, o = t - b * 384;
    float s = 0.f;
    for (int i = 0; i < 96; ++i) s += wse2[o * 96 + i] * h[b * 96 + i];
    at[t] = s + bse2[o];
  }
  __syncthreads();
  for (int t = tid; t < 384; t += 256) {
    int b = t / 192, c = t - b * 192;
    float a0 = at[b * 384 + 2 * c], a1 = at[b * 384 + 2 * c + 1];
    float m = fmaxf(a0, a1);
    float e0 = expf(a0 - m), e1 = expf(a1 - m);
    float inv = 1.f / (e0 + e1);
    attnb[t * 2 + 0] = e0 * inv;
    attnb[t * 2 + 1] = e1 * inv;
  }
}

// ---------------- K6: out = x2*p0 + k*p1 (in place: io holds x2) ----------------
__global__ __launch_bounds__(256) void k6_combine(const float* __restrict__ k,
                                                  const float* __restrict__ attnb,
                                                  float* io)
{
  const int i4 = blockIdx.x * 256 + threadIdx.x;
  const int bc = i4 >> 12;
  float p0 = attnb[bc * 2 + 0], p1 = attnb[bc * 2 + 1];
  float4 a = ((const float4*)io)[i4];
  float4 kk = ((const float4*)k)[i4];
  float4 r;
  r.x = a.x * p0 + kk.x * p1;
  r.y = a.y * p0 + kk.y * p1;
  r.z = a.z * p0 + kk.z * p1;
  r.w = a.w * p0 + kk.w * p1;
  ((float4*)io)[i4] = r;
}

extern "C" void kernel_launch(void* const* d_in, const int* in_sizes, int n_in,
                              void* d_out, int out_size, void* d_ws, size_t ws_size,
                              hipStream_t stream) {
  const float* x     = (const float*)d_in[0];
  const float* wkey  = (const float*)d_in[1];
  const float* bn1s  = (const float*)d_in[2];
  const float* bn1b  = (const float*)d_in[3];
  const float* we1   = (const float*)d_in[4];
  const float* bn2s  = (const float*)d_in[5];
  const float* bn2b  = (const float*)d_in[6];
  const float* we2   = (const float*)d_in[7];
  const float* be2   = (const float*)d_in[8];
  const float* gns   = (const float*)d_in[9];
  const float* gnb   = (const float*)d_in[10];
  const float* wc1   = (const float*)d_in[11];
  const float* bn3s  = (const float*)d_in[12];
  const float* bn3b  = (const float*)d_in[13];
  const float* bn4s  = (const float*)d_in[14];
  const float* bn4b  = (const float*)d_in[15];
  const float* wse1  = (const float*)d_in[16];
  const float* bse1  = (const float*)d_in[17];
  const float* bnses = (const float*)d_in[18];
  const float* bnseb = (const float*)d_in[19];
  const float* wse2  = (const float*)d_in[20];
  const float* bse2  = (const float*)d_in[21];

  float* ws = (float*)d_ws;
  // layout (float units); wrbuf aliases actbf (actbf dead before w-gemm writes)
  float* kbuf           = ws;                                   // 6291456
  float* vbuf           = ws + 6291456;                         // 6291456
  unsigned short* ebf   = (unsigned short*)(ws + 12582912);     // hi[2b][12][n][8] + lo (6291456 sh)
  unsigned short* actbf = (unsigned short*)(ws + 15728640);     // [2b][48][n][8] (12582912 sh)
  float* wrbuf          = ws + 15728640;                        // 7077888 (aliases actbf)
  unsigned short* apk1  = (unsigned short*)(ws + 22806528);     // 258048 sh
  unsigned short* apkV  = (unsigned short*)(ws + 22935552);     // 36864 sh
  unsigned short* apkE  = (unsigned short*)(ws + 22953984);     // 36864 sh
  unsigned short* apkW  = (unsigned short*)(ws + 22972416);     // 21504 sh
  float* gsums          = ws + 22983168;                        // 96
  float* gap            = ws + 22983264;                        // 384
  float* attnb          = ws + 22983648;                        // 768
  float* x2             = (float*)d_out;

  hipMemsetAsync(gsums, 0, 96 * sizeof(float), stream);

  prep_w<<<dim3(1008), 256, 0, stream>>>(wkey, apk1);
  prep_x<<<dim3(3072), 256, 0, stream>>>(x, actbf);
  pack_a<<<dim3(144), 256, 0, stream>>>(wc1, apkV, 192, 192);
  pack_a<<<dim3(144), 256, 0, stream>>>(we1, apkE, 96, 384);
  pack_a<<<dim3(84), 256, 0, stream>>>(we2, apkW, 224, 96);   // pad M to 224 (rows>=216 zero)

  k1_mfma<<<dim3(64, 4, 2), 256, 0, stream>>>(actbf, apk1, bn1s, bn1b, kbuf, actbf);
  // v = bn3(w_c1 @ x):        K=192 (KCH 6), M=192 (MT 12), fp32 planar out
  gemm_mfma<6, 12, 1, 0, 48><<<dim3(256, 1, 2), 256, 0, stream>>>(
      apkV, actbf, bn3s, bn3b, vbuf, nullptr, 192);
  // e = relu(bn2(w_e1 @ [x;k])): K=384 (KCH 12), M=96 (MT 6), bf16 hi/lo out
  gemm_mfma<12, 6, 0, 0, 48><<<dim3(256, 1, 2), 256, 0, stream>>>(
      apkE, actbf, bn2s, bn2b, nullptr, ebf, 96);
  // wraw = w_e2 @ e + b_e2:   K=96 (KCH 3), M=216 (MT 14), split-B (e hi+lo), fp32 out
  gemm_mfma<3, 14, 2, 1, 12><<<dim3(256, 1, 2), 256, 0, stream>>>(
      apkW, ebf, nullptr, be2, wrbuf, nullptr, 216);

  k3b_gnstats<<<dim3(8, 24, 2), 256, 0, stream>>>(wrbuf, gsums);
  k4_dynconv<<<dim3(16, 4, 16), 256, 0, stream>>>(wrbuf, vbuf, gsums, gns, gnb, bn4s, bn4b, x2);
  k5a_gap<<<dim3(384), 256, 0, stream>>>(x2, kbuf, gap);
  k5b_se<<<dim3(1), 256, 0, stream>>>(gap, wse1, bse1, bnses, bnseb, wse2, bse2, attnb);
  k6_combine<<<dim3(6144), 256, 0, stream>>>(kbuf, attnb, (float*)d_out);
}

// Round 8
// 308.107 us; speedup vs baseline: 2.1338x; 1.0216x over previous
//
#include <hip/hip_runtime.h>
#include <hip/hip_bf16.h>
#include <cstdint>

#define SP 16384

typedef __attribute__((ext_vector_type(8))) short bf16x8;
typedef __attribute__((ext_vector_type(4))) short bf16x4;
typedef __attribute__((ext_vector_type(4))) float f32x4;

__device__ inline unsigned short f2bf(float f) {
  unsigned u = __float_as_uint(f);
  unsigned r = (u + 0x7FFFu + ((u >> 16) & 1u)) >> 16;   // RNE
  return (unsigned short)r;
}
__device__ inline float bf2f(unsigned short h) {
  return __uint_as_float(((unsigned)h) << 16);
}

// ---------------- P1: pack wkey -> apk1 bf16 [g][icch6][tapch7][oc48][t4][ic8] ----------
__global__ __launch_bounds__(256) void prep_w(const float* __restrict__ wkey,
                                              unsigned short* __restrict__ apk)
{
  int e = blockIdx.x * 256 + threadIdx.x;       // 258048 total
  int ic8 = e & 7;
  int t4 = (e >> 3) & 3;
  int rest = e >> 5;
  int oc = rest % 48;  int rest2 = rest / 48;
  int tapch = rest2 % 7; int rest3 = rest2 / 7;
  int icch = rest3 % 6; int g = rest3 / 6;
  int tap = tapch * 4 + t4;
  float v = 0.f;
  if (tap < 27)
    v = wkey[((size_t)(g * 48 + oc) * 48 + icch * 8 + ic8) * 27 + tap];
  apk[e] = f2bf(v);
}

// ---------------- P2: pack x -> actbf cc 0..23 of [b][cc48][n16384][8] ----------
__global__ __launch_bounds__(256) void prep_x(const float* __restrict__ x,
                                              unsigned short* __restrict__ actbf)
{
  int t = blockIdx.x * 256 + threadIdx.x;       // 786432 total
  int n = t & 16383;
  int v = t >> 14;                              // 0..47
  int cc = v % 24, b = v / 24;
  bf16x8 pk;
  #pragma unroll
  for (int i = 0; i < 8; ++i)
    pk[i] = (short)f2bf(x[(((size_t)b * 192 + cc * 8 + i) << 14) + n]);
  *(bf16x8*)&actbf[((size_t)(b * 48 + cc) * 16384 + n) * 8] = pk;
}

// ---------------- P3: generic A-pack: src[M][K] fp32 -> [mf][kc][r16][lh4][j8] bf16 ------
__global__ __launch_bounds__(256) void pack_a(const float* __restrict__ src,
                                              unsigned short* __restrict__ dst,
                                              int M, int K)
{
  int e = blockIdx.x * 256 + threadIdx.x;       // exact grid
  int j = e & 7, lh = (e >> 3) & 3, r = (e >> 5) & 15;
  int rest = e >> 9;
  int KCH = K >> 5;
  int kc = rest % KCH, mf = rest / KCH;
  int m = mf * 16 + r, k = kc * 32 + lh * 8 + j;
  dst[e] = (m < M) ? f2bf(src[(size_t)m * K + k]) : (unsigned short)0;
}

// ---------------- K1: grouped conv 3x3x3 via bf16 MFMA + BN1 + ReLU -> k (fp32 + bf16) --
__global__ __launch_bounds__(256) void k1_mfma(
    const unsigned short* __restrict__ actbf_in, const unsigned short* __restrict__ apk,
    const float* __restrict__ bn1s, const float* __restrict__ bn1b,
    float* __restrict__ kout, unsigned short* __restrict__ actbf_out)
{
  const int tile = blockIdx.x;                  // 64 = 8 z-tiles x 8 y-tiles
  const int g = blockIdx.y;
  const int b = blockIdx.z;
  const int z0 = (tile >> 3) * 2, y0 = (tile & 7) * 4;
  const int tid = threadIdx.x;
  const int lane = tid & 63, wid = tid >> 6;
  const int ln = lane & 15, lh = lane >> 4;

  __shared__ __align__(16) unsigned short xs[4 * 6 * 34 * 8];   // 13 KB

  int offT[7];
  #pragma unroll
  for (int tc = 0; tc < 7; ++tc) {
    int tap = tc * 4 + lh; if (tap > 26) tap = 26;
    int dz = tap / 9, r = tap - dz * 9, dy = r / 3, dx = r - dy * 3;
    offT[tc] = dz * 1632 + dy * 272 + dx * 8;
  }
  const int zw = wid >> 1, yb = (wid & 1) * 2;
  int bbase[4];
  #pragma unroll
  for (int f = 0; f < 4; ++f)
    bbase[f] = zw * 1632 + (yb + (f >> 1)) * 272 + ((f & 1) * 16 + ln) * 8;

  f32x4 acc[3][4];
  #pragma unroll
  for (int m = 0; m < 3; ++m)
    #pragma unroll
    for (int f = 0; f < 4; ++f) { f32x4 z4 = {0.f, 0.f, 0.f, 0.f}; acc[m][f] = z4; }

  const unsigned short* ag = apk + (size_t)g * 6 * 7 * 1536;

  for (int icch = 0; icch < 6; ++icch) {
    __syncthreads();
    const unsigned short* xsrc = actbf_in + ((size_t)(b * 48 + g * 6 + icch) * 16384) * 8;
    for (int e = tid; e < 816; e += 256) {
      int row = e / 34, xr = e - row * 34;
      int zz = row / 6, yy = row - zz * 6;
      int gz = z0 - 1 + zz, gy = y0 - 1 + yy, gx = xr - 1;
      bf16x8 v = {0, 0, 0, 0, 0, 0, 0, 0};
      if ((unsigned)gz < 16u && (unsigned)gy < 32u && (unsigned)gx < 32u)
        v = *(const bf16x8*)&xsrc[((gz << 10) + (gy << 5) + gx) * 8];
      *(bf16x8*)&xs[row * 272 + xr * 8] = v;
    }
    __syncthreads();
    const unsigned short* ab = ag + (size_t)icch * 7 * 1536;
    #pragma unroll
    for (int tc = 0; tc < 7; ++tc) {
      bf16x8 a0 = *(const bf16x8*)&ab[tc * 1536 + (0 * 16 + ln) * 32 + lh * 8];
      bf16x8 a1 = *(const bf16x8*)&ab[tc * 1536 + (1 * 16 + ln) * 32 + lh * 8];
      bf16x8 a2 = *(const bf16x8*)&ab[tc * 1536 + (2 * 16 + ln) * 32 + lh * 8];
      bf16x8 bb[4];
      #pragma unroll
      for (int f = 0; f < 4; ++f) bb[f] = *(const bf16x8*)&xs[bbase[f] + offT[tc]];
      #pragma unroll
      for (int f = 0; f < 4; ++f) {
        acc[0][f] = __builtin_amdgcn_mfma_f32_16x16x32_bf16(a0, bb[f], acc[0][f], 0, 0, 0);
        acc[1][f] = __builtin_amdgcn_mfma_f32_16x16x32_bf16(a1, bb[f], acc[1][f], 0, 0, 0);
        acc[2][f] = __builtin_amdgcn_mfma_f32_16x16x32_bf16(a2, bb[f], acc[2][f], 0, 0, 0);
      }
    }
  }
  const int z = z0 + zw;
  #pragma unroll
  for (int mf = 0; mf < 3; ++mf) {
    #pragma unroll
    for (int f = 0; f < 4; ++f) {
      const int y = y0 + yb + (f >> 1);
      const int xq = (f & 1) * 16 + ln;
      const int n = (z << 10) + (y << 5) + xq;
      unsigned short h4[4];
      #pragma unroll
      for (int r = 0; r < 4; ++r) {
        int oc = g * 48 + mf * 16 + lh * 4 + r;
        float t = fmaxf(acc[mf][f][r] * bn1s[oc] + bn1b[oc], 0.f);
        kout[(((size_t)b * 192 + oc) << 14) + n] = t;
        h4[r] = f2bf(t);
      }
      int cc = 24 + g * 6 + mf * 2 + (lh >> 1);
      bf16x4 hv = {(short)h4[0], (short)h4[1], (short)h4[2], (short)h4[3]};
      *(bf16x4*)&actbf_out[((size_t)(b * 48 + cc) * 16384 + n) * 8 + (lh & 1) * 4] = hv;
    }
  }
}

// ---------------- K2: LDS-free bf16 MFMA 1x1 GEMM ----------------
// A: apk [mf][kc][r16][lh4][j8]; B: bact [b][BPL][16384][8] (cc = kc*4+lh)
// EPI 0: relu(v*sc+bi) -> bf16 hi/lo interleaved [b][12][n][8] (+lo at +3145728)
// EPI 1: v*sc+bi -> fp32 planar [b][Mfull][n]
// EPI 2: v+bi    -> fp32 planar, guard c<Mfull
// SPLITB: second B copy (lo) at +3145728 shorts, accumulated in.
template<int KCH, int MT, int EPI, int SPLITB, int BPL>
__global__ __launch_bounds__(256) void gemm_mfma(
    const unsigned short* __restrict__ apk,
    const unsigned short* __restrict__ bact,
    const float* __restrict__ sc, const float* __restrict__ bi,
    float* __restrict__ outf, unsigned short* __restrict__ outbf,
    int Mfull)
{
  const int b = blockIdx.z;
  const int tid = threadIdx.x;
  const int lane = tid & 63, wid = tid >> 6;
  const int ln = lane & 15, lh = lane >> 4;
  const int n = blockIdx.x * 64 + wid * 16 + ln;

  f32x4 acc[MT];
  #pragma unroll
  for (int m = 0; m < MT; ++m) { f32x4 z = {0.f, 0.f, 0.f, 0.f}; acc[m] = z; }

  const unsigned short* bb = bact + ((size_t)(b * BPL + lh) * 16384 + n) * 8;
  #pragma unroll
  for (int kc = 0; kc < KCH; ++kc) {
    bf16x8 bfr = *(const bf16x8*)(bb + (size_t)kc * 4 * 131072);
    bf16x8 bfr2;
    if (SPLITB) bfr2 = *(const bf16x8*)(bb + 3145728 + (size_t)kc * 4 * 131072);
    #pragma unroll
    for (int m = 0; m < MT; ++m) {
      bf16x8 afr = *(const bf16x8*)&apk[(((m * KCH + kc) * 16 + ln) * 4 + lh) * 8];
      acc[m] = __builtin_amdgcn_mfma_f32_16x16x32_bf16(afr, bfr, acc[m], 0, 0, 0);
      if (SPLITB)
        acc[m] = __builtin_amdgcn_mfma_f32_16x16x32_bf16(afr, bfr2, acc[m], 0, 0, 0);
    }
  }
  #pragma unroll
  for (int m = 0; m < MT; ++m) {
    int c0 = m * 16 + lh * 4;
    if (EPI == 0) {
      unsigned short h[4], l[4];
      #pragma unroll
      for (int r = 0; r < 4; ++r) {
        int c = c0 + r;
        float t = fmaxf(acc[m][r] * sc[c] + bi[c], 0.f);
        h[r] = f2bf(t);
        l[r] = f2bf(t - bf2f(h[r]));
      }
      int cc = m * 2 + (lh >> 1);
      size_t o = ((size_t)(b * 12 + cc) * 16384 + n) * 8 + (lh & 1) * 4;
      bf16x4 hv = {(short)h[0], (short)h[1], (short)h[2], (short)h[3]};
      bf16x4 lv = {(short)l[0], (short)l[1], (short)l[2], (short)l[3]};
      *(bf16x4*)&outbf[o] = hv;
      *(bf16x4*)&outbf[o + 3145728] = lv;
    } else {
      #pragma unroll
      for (int r = 0; r < 4; ++r) {
        int c = c0 + r;
        if (EPI == 2 && c >= Mfull) continue;
        float t = (EPI == 1) ? (acc[m][r] * sc[c] + bi[c]) : (acc[m][r] + bi[c]);
        outf[(((size_t)b * Mfull + c) << 14) + n] = t;
      }
    }
  }
}

// ---------------- K3b: GroupNorm stats (sum, sumsq) per (b, group of 9 ch) -------------
__global__ __launch_bounds__(256) void k3b_gnstats(const float* __restrict__ wraw,
                                                   float* __restrict__ gsums)
{
  const int chunk = blockIdx.x, g = blockIdx.y, b = blockIdx.z;
  const float4* p = (const float4*)(wraw + (((size_t)b * 216 + g * 9) << 14));
  float s1 = 0.f, s2 = 0.f;
  const int base = chunk * 4608 + threadIdx.x;
  #pragma unroll 4
  for (int i = 0; i < 18; ++i) {
    float4 v = p[base + i * 256];
    s1 += v.x + v.y + v.z + v.w;
    s2 += v.x * v.x + v.y * v.y + v.z * v.z + v.w * v.w;
  }
  #pragma unroll
  for (int o = 32; o > 0; o >>= 1) { s1 += __shfl_down(s1, o); s2 += __shfl_down(s2, o); }
  __shared__ float ps[4][2];
  int lane = threadIdx.x & 63, w = threadIdx.x >> 6;
  if (lane == 0) { ps[w][0] = s1; ps[w][1] = s2; }
  __syncthreads();
  if (threadIdx.x == 0) {
    float t1 = ps[0][0] + ps[1][0] + ps[2][0] + ps[3][0];
    float t2 = ps[0][1] + ps[1][1] + ps[2][1] + ps[3][1];
    atomicAdd(&gsums[(b * 24 + g) * 2 + 0], t1);
    atomicAdd(&gsums[(b * 24 + g) * 2 + 1], t2);
  }
}

// ---------------- K4 v2: dynamic 3x3x3 conv + BN4 + SiLU -> x2 ----------------
// wls LDS round-trip removed (each thread's weights are private -> direct L2 reads);
// ONE barrier total; vs stride 36 -> aligned b128 LDS reads, 51.8 KB -> 3 blocks/CU.
__global__ __launch_bounds__(256) void k4_dynconv(
    const float* __restrict__ wraw, const float* __restrict__ vbuf,
    const float* __restrict__ gsums,
    const float* __restrict__ gns, const float* __restrict__ gnb,
    const float* __restrict__ bn4s, const float* __restrict__ bn4b,
    float* __restrict__ x2)
{
  const int tile = blockIdx.x;
  const int z0 = (tile >> 2) * 4, y0 = (tile & 3) * 8;
  const int cs = blockIdx.y;
  const int b = blockIdx.z >> 3, gw = blockIdx.z & 7;
  const int tid = threadIdx.x;
  const int tx = (tid & 7) * 4, ty = (tid >> 3) & 7, tz = tid >> 6;

  __shared__ __align__(16) float vs[6][6][10][36];   // 51.84 KB, stride 36 (aligned b128)

  float mu[3], rs[3];
  #pragma unroll
  for (int j = 0; j < 3; ++j) {
    int gr = gw * 3 + j;
    float m1 = gsums[(b * 24 + gr) * 2 + 0] * (1.f / 147456.f);
    float m2 = gsums[(b * 24 + gr) * 2 + 1] * (1.f / 147456.f);
    mu[j] = m1;
    rs[j] = rsqrtf(m2 - m1 * m1 + 1e-5f);
  }
  const int c0 = gw * 24 + cs * 6;
  for (int e = tid; e < 6 * 2040; e += 256) {
    int cc = e / 2040; int r = e - cc * 2040;
    int zz = r / 340;  int r2 = r - zz * 340;
    int yy = r2 / 34;  int xx = r2 - yy * 34;
    int gz = z0 - 1 + zz, gy = y0 - 1 + yy, gx = xx - 1;
    float val = 0.f;
    if (gz >= 0 && gz < 16 && gy >= 0 && gy < 32 && gx >= 0 && gx < 32)
      val = vbuf[(((size_t)b * 192 + c0 + cc) << 14) + (gz << 10) + (gy << 5) + gx];
    vs[cc][zz][yy][xx] = val;
  }
  __syncthreads();                                   // the ONLY barrier

  // per-thread weight base: this thread's own 4-x output span, tap t at +t*16384
  const float* wp = wraw + (((size_t)b * 216 + gw * 27) << 14) +
                    ((z0 + tz) << 10) + ((y0 + ty) << 5) + tx;

  float acc[6][4] = {};
  #pragma unroll
  for (int chnk = 0; chnk < 9; ++chnk) {             // (dz,dy)
    const int dz = chnk / 3, dy = chnk - dz * 3;
    // issue this chunk's 3 weight loads first (hide L2 latency under LDS reads)
    float4 wv0 = *(const float4*)(wp + ((size_t)(chnk * 3 + 0) << 14));
    float4 wv1 = *(const float4*)(wp + ((size_t)(chnk * 3 + 1) << 14));
    float4 wv2 = *(const float4*)(wp + ((size_t)(chnk * 3 + 2) << 14));
    float xv[6][8];
    #pragma unroll
    for (int cc = 0; cc < 6; ++cc) {
      float4 xa = *(const float4*)&vs[cc][tz + dz][ty + dy][tx];
      float4 xb = *(const float4*)&vs[cc][tz + dz][ty + dy][tx + 4];
      xv[cc][0] = xa.x; xv[cc][1] = xa.y; xv[cc][2] = xa.z; xv[cc][3] = xa.w;
      xv[cc][4] = xb.x; xv[cc][5] = xb.y; xv[cc][6] = xb.z; xv[cc][7] = xb.w;
    }
    #pragma unroll
    for (int dxi = 0; dxi < 3; ++dxi) {
      const int cw = gw * 27 + chnk * 3 + dxi;
      const float scw = rs[dz] * gns[cw];            // uniform -> SGPR
      const float shw = gnb[cw] - mu[dz] * scw;
      float4 wv = (dxi == 0) ? wv0 : (dxi == 1) ? wv1 : wv2;
      float w4[4];
      w4[0] = wv.x * scw + shw; w4[1] = wv.y * scw + shw;
      w4[2] = wv.z * scw + shw; w4[3] = wv.w * scw + shw;
      #pragma unroll
      for (int cc = 0; cc < 6; ++cc)
        #pragma unroll
        for (int xi = 0; xi < 4; ++xi)
          acc[cc][xi] += w4[xi] * xv[cc][dxi + xi];
    }
  }
  #pragma unroll
  for (int cc = 0; cc < 6; ++cc) {
    int c = c0 + cc;
    float scv = bn4s[c], bb = bn4b[c];
    float4 r;
    float t;
    t = acc[cc][0] * scv + bb; r.x = t / (1.f + expf(-t));
    t = acc[cc][1] * scv + bb; r.y = t / (1.f + expf(-t));
    t = acc[cc][2] * scv + bb; r.z = t / (1.f + expf(-t));
    t = acc[cc][3] * scv + bb; r.w = t / (1.f + expf(-t));
    *(float4*)&x2[(((size_t)b * 192 + c) << 14) + ((z0 + tz) << 10) + ((y0 + ty) << 5) + tx] = r;
  }
}

// ---------------- K5a: gap[b][c] = mean_s(x2 + k) ----------------
__global__ __launch_bounds__(256) void k5a_gap(const float* __restrict__ x2,
                                               const float* __restrict__ k,
                                               float* __restrict__ gap)
{
  const int bc = blockIdx.x;
  const float4* p1 = (const float4*)(x2 + ((size_t)bc << 14));
  const float4* p2 = (const float4*)(k + ((size_t)bc << 14));
  float s = 0.f;
  for (int i = threadIdx.x; i < 4096; i += 256) {
    float4 a = p1[i], b2 = p2[i];
    s += (a.x + b2.x) + (a.y + b2.y) + (a.z + b2.z) + (a.w + b2.w);
  }
  #pragma unroll
  for (int o = 32; o > 0; o >>= 1) s += __shfl_down(s, o);
  __shared__ float ps[4];
  if ((threadIdx.x & 63) == 0) ps[threadIdx.x >> 6] = s;
  __syncthreads();
  if (threadIdx.x == 0) gap[bc] = (ps[0] + ps[1] + ps[2] + ps[3]) * (1.f / 16384.f);
}

// ---------------- K5b: SE head -> per-channel softmax pair ----------------
__global__ __launch_bounds__(256) void k5b_se(
    const float* __restrict__ gap,
    const float* __restrict__ wse1, const float* __restrict__ bse1,
    const float* __restrict__ bnses, const float* __restrict__ bnseb,
    const float* __restrict__ wse2, const float* __restrict__ bse2,
    float* __restrict__ attnb)
{
  __shared__ float g[384];
  __shared__ float h[192];
  __shared__ float at[768];
  const int tid = threadIdx.x;
  for (int t = tid; t < 384; t += 256) g[t] = gap[t];
  __syncthreads();
  if (tid < 192) {
    int b = tid / 96, o = tid - b * 96;
    float s = 0.f;
    for (int i = 0; i < 192; ++i) s += wse1[o * 192 + i] * g[b * 192 + i];
    s = (s + bse1[o]) * bnses[o] + bnseb[o];
    h[tid] = fmaxf(s, 0.f);
  }
  __syncthreads();
  for (int t = tid; t < 768; t += 256) {
    int b = t / 384, o = t - b * 384;
    float s = 0.f;
    for (int i = 0; i < 96; ++i) s += wse2[o * 96 + i] * h[b * 96 + i];
    at[t] = s + bse2[o];
  }
  __syncthreads();
  for (int t = tid; t < 384; t += 256) {
    int b = t / 192, c = t - b * 192;
    float a0 = at[b * 384 + 2 * c], a1 = at[b * 384 + 2 * c + 1];
    float m = fmaxf(a0, a1);
    float e0 = expf(a0 - m), e1 = expf(a1 - m);
    float inv = 1.f / (e0 + e1);
    attnb[t * 2 + 0] = e0 * inv;
    attnb[t * 2 + 1] = e1 * inv;
  }
}

// ---------------- K6: out = x2*p0 + k*p1 (in place: io holds x2) ----------------
__global__ __launch_bounds__(256) void k6_combine(const float* __restrict__ k,
                                                  const float* __restrict__ attnb,
                                                  float* io)
{
  const int i4 = blockIdx.x * 256 + threadIdx.x;
  const int bc = i4 >> 12;
  float p0 = attnb[bc * 2 + 0], p1 = attnb[bc * 2 + 1];
  float4 a = ((const float4*)io)[i4];
  float4 kk = ((const float4*)k)[i4];
  float4 r;
  r.x = a.x * p0 + kk.x * p1;
  r.y = a.y * p0 + kk.y * p1;
  r.z = a.z * p0 + kk.z * p1;
  r.w = a.w * p0 + kk.w * p1;
  ((float4*)io)[i4] = r;
}

extern "C" void kernel_launch(void* const* d_in, const int* in_sizes, int n_in,
                              void* d_out, int out_size, void* d_ws, size_t ws_size,
                              hipStream_t stream) {
  const float* x     = (const float*)d_in[0];
  const float* wkey  = (const float*)d_in[1];
  const float* bn1s  = (const float*)d_in[2];
  const float* bn1b  = (const float*)d_in[3];
  const float* we1   = (const float*)d_in[4];
  const float* bn2s  = (const float*)d_in[5];
  const float* bn2b  = (const float*)d_in[6];
  const float* we2   = (const float*)d_in[7];
  const float* be2   = (const float*)d_in[8];
  const float* gns   = (const float*)d_in[9];
  const float* gnb   = (const float*)d_in[10];
  const float* wc1   = (const float*)d_in[11];
  const float* bn3s  = (const float*)d_in[12];
  const float* bn3b  = (const float*)d_in[13];
  const float* bn4s  = (const float*)d_in[14];
  const float* bn4b  = (const float*)d_in[15];
  const float* wse1  = (const float*)d_in[16];
  const float* bse1  = (const float*)d_in[17];
  const float* bnses = (const float*)d_in[18];
  const float* bnseb = (const float*)d_in[19];
  const float* wse2  = (const float*)d_in[20];
  const float* bse2  = (const float*)d_in[21];

  float* ws = (float*)d_ws;
  // layout (float units); wrbuf aliases actbf (actbf dead before w-gemm writes)
  float* kbuf           = ws;                                   // 6291456
  float* vbuf           = ws + 6291456;                         // 6291456
  unsigned short* ebf   = (unsigned short*)(ws + 12582912);     // hi[2b][12][n][8] + lo (6291456 sh)
  unsigned short* actbf = (unsigned short*)(ws + 15728640);     // [2b][48][n][8] (12582912 sh)
  float* wrbuf          = ws + 15728640;                        // 7077888 (aliases actbf)
  unsigned short* apk1  = (unsigned short*)(ws + 22806528);     // 258048 sh
  unsigned short* apkV  = (unsigned short*)(ws + 22935552);     // 36864 sh
  unsigned short* apkE  = (unsigned short*)(ws + 22953984);     // 36864 sh
  unsigned short* apkW  = (unsigned short*)(ws + 22972416);     // 21504 sh
  float* gsums          = ws + 22983168;                        // 96
  float* gap            = ws + 22983264;                        // 384
  float* attnb          = ws + 22983648;                        // 768
  float* x2             = (float*)d_out;

  hipMemsetAsync(gsums, 0, 96 * sizeof(float), stream);

  prep_w<<<dim3(1008), 256, 0, stream>>>(wkey, apk1);
  prep_x<<<dim3(3072), 256, 0, stream>>>(x, actbf);
  pack_a<<<dim3(144), 256, 0, stream>>>(wc1, apkV, 192, 192);
  pack_a<<<dim3(144), 256, 0, stream>>>(we1, apkE, 96, 384);
  pack_a<<<dim3(84), 256, 0, stream>>>(we2, apkW, 224, 96);   // pad M to 224 (rows>=216 zero)

  k1_mfma<<<dim3(64, 4, 2), 256, 0, stream>>>(actbf, apk1, bn1s, bn1b, kbuf, actbf);
  // v = bn3(w_c1 @ x):        K=192 (KCH 6), M=192 (MT 12), fp32 planar out
  gemm_mfma<6, 12, 1, 0, 48><<<dim3(256, 1, 2), 256, 0, stream>>>(
      apkV, actbf, bn3s, bn3b, vbuf, nullptr, 192);
  // e = relu(bn2(w_e1 @ [x;k])): K=384 (KCH 12), M=96 (MT 6), bf16 hi/lo out
  gemm_mfma<12, 6, 0, 0, 48><<<dim3(256, 1, 2), 256, 0, stream>>>(
      apkE, actbf, bn2s, bn2b, nullptr, ebf, 96);
  // wraw = w_e2 @ e + b_e2:   K=96 (KCH 3), M=216 (MT 14), split-B (e hi+lo), fp32 out
  gemm_mfma<3, 14, 2, 1, 12><<<dim3(256, 1, 2), 256, 0, stream>>>(
      apkW, ebf, nullptr, be2, wrbuf, nullptr, 216);

  k3b_gnstats<<<dim3(8, 24, 2), 256, 0, stream>>>(wrbuf, gsums);
  k4_dynconv<<<dim3(16, 4, 16), 256, 0, stream>>>(wrbuf, vbuf, gsums, gns, gnb, bn4s, bn4b, x2);
  k5a_gap<<<dim3(384), 256, 0, stream>>>(x2, kbuf, gap);
  k5b_se<<<dim3(1), 256, 0, stream>>>(gap, wse1, bse1, bnses, bnseb, wse2, bse2, attnb);
  k6_combine<<<dim3(6144), 256, 0, stream>>>(kbuf, attnb, (float*)d_out);
}

// Round 10
// 277.229 us; speedup vs baseline: 2.3714x; 1.1114x over previous
//
#include <hip/hip_runtime.h>
#include <hip/hip_bf16.h>
#include <cstdint>

#define SP 16384

typedef __attribute__((ext_vector_type(8))) short bf16x8;
typedef __attribute__((ext_vector_type(4))) short bf16x4;
typedef __attribute__((ext_vector_type(4))) float f32x4;

__device__ inline unsigned short f2bf(float f) {
  unsigned u = __float_as_uint(f);
  unsigned r = (u + 0x7FFFu + ((u >> 16) & 1u)) >> 16;   // RNE
  return (unsigned short)r;
}
__device__ inline float bf2f(unsigned short h) {
  return __uint_as_float(((unsigned)h) << 16);
}

// ---------------- P1: pack wkey -> apk1 bf16 [g][icch6][tapch7][oc48][t4][ic8] ----------
__global__ __launch_bounds__(256) void prep_w(const float* __restrict__ wkey,
                                              unsigned short* __restrict__ apk)
{
  int e = blockIdx.x * 256 + threadIdx.x;       // 258048 total
  int ic8 = e & 7;
  int t4 = (e >> 3) & 3;
  int rest = e >> 5;
  int oc = rest % 48;  int rest2 = rest / 48;
  int tapch = rest2 % 7; int rest3 = rest2 / 7;
  int icch = rest3 % 6; int g = rest3 / 6;
  int tap = tapch * 4 + t4;
  float v = 0.f;
  if (tap < 27)
    v = wkey[((size_t)(g * 48 + oc) * 48 + icch * 8 + ic8) * 27 + tap];
  apk[e] = f2bf(v);
}

// ---------------- P2: pack x -> actbf cc 0..23 of [b][cc48][n16384][8] ----------
__global__ __launch_bounds__(256) void prep_x(const float* __restrict__ x,
                                              unsigned short* __restrict__ actbf)
{
  int t = blockIdx.x * 256 + threadIdx.x;       // 786432 total
  int n = t & 16383;
  int v = t >> 14;                              // 0..47
  int cc = v % 24, b = v / 24;
  bf16x8 pk;
  #pragma unroll
  for (int i = 0; i < 8; ++i)
    pk[i] = (short)f2bf(x[(((size_t)b * 192 + cc * 8 + i) << 14) + n]);
  *(bf16x8*)&actbf[((size_t)(b * 48 + cc) * 16384 + n) * 8] = pk;
}

// ---------------- P3: generic A-pack: src[M][K] fp32 -> [mf][kc][r16][lh4][j8] bf16 ------
__global__ __launch_bounds__(256) void pack_a(const float* __restrict__ src,
                                              unsigned short* __restrict__ dst,
                                              int M, int K)
{
  int e = blockIdx.x * 256 + threadIdx.x;       // exact grid
  int j = e & 7, lh = (e >> 3) & 3, r = (e >> 5) & 15;
  int rest = e >> 9;
  int KCH = K >> 5;
  int kc = rest % KCH, mf = rest / KCH;
  int m = mf * 16 + r, k = kc * 32 + lh * 8 + j;
  dst[e] = (m < M) ? f2bf(src[(size_t)m * K + k]) : (unsigned short)0;
}

// ---------------- K1: grouped conv 3x3x3 via bf16 MFMA + BN1 + ReLU -> k (fp32 + bf16) --
__global__ __launch_bounds__(256) void k1_mfma(
    const unsigned short* __restrict__ actbf_in, const unsigned short* __restrict__ apk,
    const float* __restrict__ bn1s, const float* __restrict__ bn1b,
    float* __restrict__ kout, unsigned short* __restrict__ actbf_out)
{
  const int tile = blockIdx.x;                  // 64 = 8 z-tiles x 8 y-tiles
  const int g = blockIdx.y;
  const int b = blockIdx.z;
  const int z0 = (tile >> 3) * 2, y0 = (tile & 7) * 4;
  const int tid = threadIdx.x;
  const int lane = tid & 63, wid = tid >> 6;
  const int ln = lane & 15, lh = lane >> 4;

  __shared__ __align__(16) unsigned short xs[4 * 6 * 34 * 8];   // 13 KB

  int offT[7];
  #pragma unroll
  for (int tc = 0; tc < 7; ++tc) {
    int tap = tc * 4 + lh; if (tap > 26) tap = 26;
    int dz = tap / 9, r = tap - dz * 9, dy = r / 3, dx = r - dy * 3;
    offT[tc] = dz * 1632 + dy * 272 + dx * 8;
  }
  const int zw = wid >> 1, yb = (wid & 1) * 2;
  int bbase[4];
  #pragma unroll
  for (int f = 0; f < 4; ++f)
    bbase[f] = zw * 1632 + (yb + (f >> 1)) * 272 + ((f & 1) * 16 + ln) * 8;

  f32x4 acc[3][4];
  #pragma unroll
  for (int m = 0; m < 3; ++m)
    #pragma unroll
    for (int f = 0; f < 4; ++f) { f32x4 z4 = {0.f, 0.f, 0.f, 0.f}; acc[m][f] = z4; }

  const unsigned short* ag = apk + (size_t)g * 6 * 7 * 1536;

  for (int icch = 0; icch < 6; ++icch) {
    __syncthreads();
    const unsigned short* xsrc = actbf_in + ((size_t)(b * 48 + g * 6 + icch) * 16384) * 8;
    for (int e = tid; e < 816; e += 256) {
      int row = e / 34, xr = e - row * 34;
      int zz = row / 6, yy = row - zz * 6;
      int gz = z0 - 1 + zz, gy = y0 - 1 + yy, gx = xr - 1;
      bf16x8 v = {0, 0, 0, 0, 0, 0, 0, 0};
      if ((unsigned)gz < 16u && (unsigned)gy < 32u && (unsigned)gx < 32u)
        v = *(const bf16x8*)&xsrc[((gz << 10) + (gy << 5) + gx) * 8];
      *(bf16x8*)&xs[row * 272 + xr * 8] = v;
    }
    __syncthreads();
    const unsigned short* ab = ag + (size_t)icch * 7 * 1536;
    #pragma unroll
    for (int tc = 0; tc < 7; ++tc) {
      bf16x8 a0 = *(const bf16x8*)&ab[tc * 1536 + (0 * 16 + ln) * 32 + lh * 8];
      bf16x8 a1 = *(const bf16x8*)&ab[tc * 1536 + (1 * 16 + ln) * 32 + lh * 8];
      bf16x8 a2 = *(const bf16x8*)&ab[tc * 1536 + (2 * 16 + ln) * 32 + lh * 8];
      bf16x8 bb[4];
      #pragma unroll
      for (int f = 0; f < 4; ++f) bb[f] = *(const bf16x8*)&xs[bbase[f] + offT[tc]];
      #pragma unroll
      for (int f = 0; f < 4; ++f) {
        acc[0][f] = __builtin_amdgcn_mfma_f32_16x16x32_bf16(a0, bb[f], acc[0][f], 0, 0, 0);
        acc[1][f] = __builtin_amdgcn_mfma_f32_16x16x32_bf16(a1, bb[f], acc[1][f], 0, 0, 0);
        acc[2][f] = __builtin_amdgcn_mfma_f32_16x16x32_bf16(a2, bb[f], acc[2][f], 0, 0, 0);
      }
    }
  }
  const int z = z0 + zw;
  #pragma unroll
  for (int mf = 0; mf < 3; ++mf) {
    #pragma unroll
    for (int f = 0; f < 4; ++f) {
      const int y = y0 + yb + (f >> 1);
      const int xq = (f & 1) * 16 + ln;
      const int n = (z << 10) + (y << 5) + xq;
      unsigned short h4[4];
      #pragma unroll
      for (int r = 0; r < 4; ++r) {
        int oc = g * 48 + mf * 16 + lh * 4 + r;
        float t = fmaxf(acc[mf][f][r] * bn1s[oc] + bn1b[oc], 0.f);
        kout[(((size_t)b * 192 + oc) << 14) + n] = t;
        h4[r] = f2bf(t);
      }
      int cc = 24 + g * 6 + mf * 2 + (lh >> 1);
      bf16x4 hv = {(short)h4[0], (short)h4[1], (short)h4[2], (short)h4[3]};
      *(bf16x4*)&actbf_out[((size_t)(b * 48 + cc) * 16384 + n) * 8 + (lh & 1) * 4] = hv;
    }
  }
}

// ---------------- K2: LDS-free bf16 MFMA 1x1 GEMM ----------------
// A: apk [mf][kc][r16][lh4][j8]; B: bact [b][BPL][16384][8] (cc = kc*4+lh)
// EPI 0: relu(v*sc+bi) -> bf16 hi/lo interleaved [b][12][n][8] (+lo at +3145728)
// EPI 1: v*sc+bi -> fp32 planar [b][Mfull][n]
// EPI 2: v+bi    -> fp32 planar, guard c<Mfull
// SPLITB: second B copy (lo) at +3145728 shorts, accumulated in.
template<int KCH, int MT, int EPI, int SPLITB, int BPL>
__global__ __launch_bounds__(256) void gemm_mfma(
    const unsigned short* __restrict__ apk,
    const unsigned short* __restrict__ bact,
    const float* __restrict__ sc, const float* __restrict__ bi,
    float* __restrict__ outf, unsigned short* __restrict__ outbf,
    int Mfull)
{
  const int b = blockIdx.z;
  const int tid = threadIdx.x;
  const int lane = tid & 63, wid = tid >> 6;
  const int ln = lane & 15, lh = lane >> 4;
  const int n = blockIdx.x * 64 + wid * 16 + ln;

  f32x4 acc[MT];
  #pragma unroll
  for (int m = 0; m < MT; ++m) { f32x4 z = {0.f, 0.f, 0.f, 0.f}; acc[m] = z; }

  const unsigned short* bb = bact + ((size_t)(b * BPL + lh) * 16384 + n) * 8;
  #pragma unroll
  for (int kc = 0; kc < KCH; ++kc) {
    bf16x8 bfr = *(const bf16x8*)(bb + (size_t)kc * 4 * 131072);
    bf16x8 bfr2;
    if (SPLITB) bfr2 = *(const bf16x8*)(bb + 3145728 + (size_t)kc * 4 * 131072);
    #pragma unroll
    for (int m = 0; m < MT; ++m) {
      bf16x8 afr = *(const bf16x8*)&apk[(((m * KCH + kc) * 16 + ln) * 4 + lh) * 8];
      acc[m] = __builtin_amdgcn_mfma_f32_16x16x32_bf16(afr, bfr, acc[m], 0, 0, 0);
      if (SPLITB)
        acc[m] = __builtin_amdgcn_mfma_f32_16x16x32_bf16(afr, bfr2, acc[m], 0, 0, 0);
    }
  }
  #pragma unroll
  for (int m = 0; m < MT; ++m) {
    int c0 = m * 16 + lh * 4;
    if (EPI == 0) {
      unsigned short h[4], l[4];
      #pragma unroll
      for (int r = 0; r < 4; ++r) {
        int c = c0 + r;
        float t = fmaxf(acc[m][r] * sc[c] + bi[c], 0.f);
        h[r] = f2bf(t);
        l[r] = f2bf(t - bf2f(h[r]));
      }
      int cc = m * 2 + (lh >> 1);
      size_t o = ((size_t)(b * 12 + cc) * 16384 + n) * 8 + (lh & 1) * 4;
      bf16x4 hv = {(short)h[0], (short)h[1], (short)h[2], (short)h[3]};
      bf16x4 lv = {(short)l[0], (short)l[1], (short)l[2], (short)l[3]};
      *(bf16x4*)&outbf[o] = hv;
      *(bf16x4*)&outbf[o + 3145728] = lv;
    } else {
      #pragma unroll
      for (int r = 0; r < 4; ++r) {
        int c = c0 + r;
        if (EPI == 2 && c >= Mfull) continue;
        float t = (EPI == 1) ? (acc[m][r] * sc[c] + bi[c]) : (acc[m][r] + bi[c]);
        outf[(((size_t)b * Mfull + c) << 14) + n] = t;
      }
    }
  }
}

// ---------------- K3b: GroupNorm stats (sum, sumsq) per (b, group of 9 ch) -------------
__global__ __launch_bounds__(256) void k3b_gnstats(const float* __restrict__ wraw,
                                                   float* __restrict__ gsums)
{
  const int chunk = blockIdx.x, g = blockIdx.y, b = blockIdx.z;
  const float4* p = (const float4*)(wraw + (((size_t)b * 216 + g * 9) << 14));
  float s1 = 0.f, s2 = 0.f;
  const int base = chunk * 4608 + threadIdx.x;
  #pragma unroll 4
  for (int i = 0; i < 18; ++i) {
    float4 v = p[base + i * 256];
    s1 += v.x + v.y + v.z + v.w;
    s2 += v.x * v.x + v.y * v.y + v.z * v.z + v.w * v.w;
  }
  #pragma unroll
  for (int o = 32; o > 0; o >>= 1) { s1 += __shfl_down(s1, o); s2 += __shfl_down(s2, o); }
  __shared__ float ps[4][2];
  int lane = threadIdx.x & 63, w = threadIdx.x >> 6;
  if (lane == 0) { ps[w][0] = s1; ps[w][1] = s2; }
  __syncthreads();
  if (threadIdx.x == 0) {
    float t1 = ps[0][0] + ps[1][0] + ps[2][0] + ps[3][0];
    float t2 = ps[0][1] + ps[1][1] + ps[2][1] + ps[3][1];
    atomicAdd(&gsums[(b * 24 + g) * 2 + 0], t1);
    atomicAdd(&gsums[(b * 24 + g) * 2 + 1], t2);
  }
}

// ---------------- K4 v3: dynamic 3x3x3 conv + BN4 + SiLU -> x2 ----------------
// 3 ch/block (LDS 25.9 KB -> 6 blocks/CU); vectorized float4 staging (x-halos are
// always-zero since tile spans full x); weights register-direct from L2; 1 barrier.
__global__ __launch_bounds__(256) void k4_dynconv(
    const float* __restrict__ wraw, const float* __restrict__ vbuf,
    const float* __restrict__ gsums,
    const float* __restrict__ gns, const float* __restrict__ gnb,
    const float* __restrict__ bn4s, const float* __restrict__ bn4b,
    float* __restrict__ x2)
{
  const int tile = blockIdx.x;
  const int z0 = (tile >> 2) * 4, y0 = (tile & 3) * 8;
  const int cs = blockIdx.y;                         // 0..7, 3 channels each
  const int b = blockIdx.z >> 3, gw = blockIdx.z & 7;
  const int tid = threadIdx.x;
  const int tx = (tid & 7) * 4, ty = (tid >> 3) & 7, tz = tid >> 6;

  __shared__ __align__(16) float vs[3][6][10][36];   // 25.9 KB

  float mu[3], rs[3];
  #pragma unroll
  for (int j = 0; j < 3; ++j) {
    int gr = gw * 3 + j;
    float m1 = gsums[(b * 24 + gr) * 2 + 0] * (1.f / 147456.f);
    float m2 = gsums[(b * 24 + gr) * 2 + 1] * (1.f / 147456.f);
    mu[j] = m1;
    rs[j] = rsqrtf(m2 - m1 * m1 + 1e-5f);
  }
  const int c0 = gw * 24 + cs * 3;

  // staged rows: 180 = 3cc x 6zz x 10yy, each 8 aligned float4 (32 interior x)
  #pragma unroll
  for (int i = 0; i < 6; ++i) {
    int e = tid + i * 256;                           // < 1536, guard 1440
    if (e < 1440) {
      int q = e & 7;
      int row = e >> 3;
      int cc = row / 60;
      int rem = row - cc * 60;
      int zz = rem / 10;
      int yy = rem - zz * 10;
      int gz = z0 - 1 + zz, gy = y0 - 1 + yy;
      float4 v4 = {0.f, 0.f, 0.f, 0.f};
      if ((unsigned)gz < 16u && (unsigned)gy < 32u)
        v4 = *(const float4*)&vbuf[(((size_t)b * 192 + c0 + cc) << 14) +
                                   (gz << 10) + (gy << 5) + q * 4];
      float* dst = &vs[cc][zz][yy][1 + q * 4];       // data at [1..32]
      dst[0] = v4.x; dst[1] = v4.y; dst[2] = v4.z; dst[3] = v4.w;
    }
  }
  // zero halos [0] and [33] (always out-of-range in x)
  for (int e = tid; e < 360; e += 256) {
    int row = e >> 1, side = e & 1;
    int cc = row / 60;
    int rem = row - cc * 60;
    int zz = rem / 10;
    int yy = rem - zz * 10;
    vs[cc][zz][yy][side ? 33 : 0] = 0.f;
  }
  __syncthreads();                                   // the ONLY barrier

  const float* wp = wraw + (((size_t)b * 216 + gw * 27) << 14) +
                    ((z0 + tz) << 10) + ((y0 + ty) << 5) + tx;

  float acc[3][4] = {};
  #pragma unroll
  for (int dz = 0; dz < 3; ++dz) {
    #pragma unroll
    for (int dy = 0; dy < 3; ++dy) {
      const int chnk = dz * 3 + dy;
      float4 wv0 = *(const float4*)(wp + ((size_t)(chnk * 3 + 0) << 14));
      float4 wv1 = *(const float4*)(wp + ((size_t)(chnk * 3 + 1) << 14));
      float4 wv2 = *(const float4*)(wp + ((size_t)(chnk * 3 + 2) << 14));
      float xv[3][8];
      #pragma unroll
      for (int cc = 0; cc < 3; ++cc) {
        float4 xa = *(const float4*)&vs[cc][tz + dz][ty + dy][tx];
        float4 xb = *(const float4*)&vs[cc][tz + dz][ty + dy][tx + 4];
        xv[cc][0] = xa.x; xv[cc][1] = xa.y; xv[cc][2] = xa.z; xv[cc][3] = xa.w;
        xv[cc][4] = xb.x; xv[cc][5] = xb.y; xv[cc][6] = xb.z; xv[cc][7] = xb.w;
      }
      #pragma unroll
      for (int dxi = 0; dxi < 3; ++dxi) {
        const int cw = gw * 27 + chnk * 3 + dxi;
        const float scw = rs[dz] * gns[cw];
        const float shw = gnb[cw] - mu[dz] * scw;
        float4 wv = (dxi == 0) ? wv0 : (dxi == 1) ? wv1 : wv2;
        float w4[4];
        w4[0] = wv.x * scw + shw; w4[1] = wv.y * scw + shw;
        w4[2] = wv.z * scw + shw; w4[3] = wv.w * scw + shw;
        #pragma unroll
        for (int cc = 0; cc < 3; ++cc)
          #pragma unroll
          for (int xi = 0; xi < 4; ++xi)
            acc[cc][xi] += w4[xi] * xv[cc][dxi + xi];
      }
    }
  }
  #pragma unroll
  for (int cc = 0; cc < 3; ++cc) {
    int c = c0 + cc;
    float scv = bn4s[c], bb = bn4b[c];
    float4 r;
    float t;
    t = acc[cc][0] * scv + bb; r.x = t / (1.f + expf(-t));
    t = acc[cc][1] * scv + bb; r.y = t / (1.f + expf(-t));
    t = acc[cc][2] * scv + bb; r.z = t / (1.f + expf(-t));
    t = acc[cc][3] * scv + bb; r.w = t / (1.f + expf(-t));
    *(float4*)&x2[(((size_t)b * 192 + c) << 14) + ((z0 + tz) << 10) + ((y0 + ty) << 5) + tx] = r;
  }
}

// ---------------- K5a: gap[b][c] = mean_s(x2 + k) ----------------
__global__ __launch_bounds__(256) void k5a_gap(const float* __restrict__ x2,
                                               const float* __restrict__ k,
                                               float* __restrict__ gap)
{
  const int bc = blockIdx.x;
  const float4* p1 = (const float4*)(x2 + ((size_t)bc << 14));
  const float4* p2 = (const float4*)(k + ((size_t)bc << 14));
  float s = 0.f;
  for (int i = threadIdx.x; i < 4096; i += 256) {
    float4 a = p1[i], b2 = p2[i];
    s += (a.x + b2.x) + (a.y + b2.y) + (a.z + b2.z) + (a.w + b2.w);
  }
  #pragma unroll
  for (int o = 32; o > 0; o >>= 1) s += __shfl_down(s, o);
  __shared__ float ps[4];
  if ((threadIdx.x & 63) == 0) ps[threadIdx.x >> 6] = s;
  __syncthreads();
  if (threadIdx.x == 0) gap[bc] = (ps[0] + ps[1] + ps[2] + ps[3]) * (1.f / 16384.f);
}

// ---------------- K5b: SE head -> per-channel softmax pair ----------------
__global__ __launch_bounds__(256) void k5b_se(
    const float* __restrict__ gap,
    const float* __restrict__ wse1, const float* __restrict__ bse1,
    const float* __restrict__ bnses, const float* __restrict__ bnseb,
    const float* __restrict__ wse2, const float* __restrict__ bse2,
    float* __restrict__ attnb)
{
  __shared__ float g[384];
  __shared__ float h[192];
  __shared__ float at[768];
  const int tid = threadIdx.x;
  for (int t = tid; t < 384; t += 256) g[t] = gap[t];
  __syncthreads();
  if (tid < 192) {
    int b = tid / 96, o = tid - b * 96;
    float s = 0.f;
    for (int i = 0; i < 192; ++i) s += wse1[o * 192 + i] * g[b * 192 + i];
    s = (s + bse1[o]) * bnses[o] + bnseb[o];
    h[tid] = fmaxf(s, 0.f);
  }
  __syncthreads();
  for (int t = tid; t < 768; t += 256) {
    int b = t / 384, o = t - b * 384;
    float s = 0.f;
    for (int i = 0; i < 96; ++i) s += wse2[o * 96 + i] * h[b * 96 + i];
    at[t] = s + bse2[o];
  }
  __syncthreads();
  for (int t = tid; t < 384; t += 256) {
    int b = t / 192, c = t - b * 192;
    float a0 = at[b * 384 + 2 * c], a1 = at[b * 384 + 2 * c + 1];
    float m = fmaxf(a0, a1);
    float e0 = expf(a0 - m), e1 = expf(a1 - m);
    float inv = 1.f / (e0 + e1);
    attnb[t * 2 + 0] = e0 * inv;
    attnb[t * 2 + 1] = e1 * inv;
  }
}

// ---------------- K6: out = x2*p0 + k*p1 (in place: io holds x2) ----------------
__global__ __launch_bounds__(256) void k6_combine(const float* __restrict__ k,
                                                  const float* __restrict__ attnb,
                                                  float* io)
{
  const int i4 = blockIdx.x * 256 + threadIdx.x;
  const int bc = i4 >> 12;
  float p0 = attnb[bc * 2 + 0], p1 = attnb[bc * 2 + 1];
  float4 a = ((const float4*)io)[i4];
  float4 kk = ((const float4*)k)[i4];
  float4 r;
  r.x = a.x * p0 + kk.x * p1;
  r.y = a.y * p0 + kk.y * p1;
  r.z = a.z * p0 + kk.z * p1;
  r.w = a.w * p0 + kk.w * p1;
  ((float4*)io)[i4] = r;
}

extern "C" void kernel_launch(void* const* d_in, const int* in_sizes, int n_in,
                              void* d_out, int out_size, void* d_ws, size_t ws_size,
                              hipStream_t stream) {
  const float* x     = (const float*)d_in[0];
  const float* wkey  = (const float*)d_in[1];
  const float* bn1s  = (const float*)d_in[2];
  const float* bn1b  = (const float*)d_in[3];
  const float* we1   = (const float*)d_in[4];
  const float* bn2s  = (const float*)d_in[5];
  const float* bn2b  = (const float*)d_in[6];
  const float* we2   = (const float*)d_in[7];
  const float* be2   = (const float*)d_in[8];
  const float* gns   = (const float*)d_in[9];
  const float* gnb   = (const float*)d_in[10];
  const float* wc1   = (const float*)d_in[11];
  const float* bn3s  = (const float*)d_in[12];
  const float* bn3b  = (const float*)d_in[13];
  const float* bn4s  = (const float*)d_in[14];
  const float* bn4b  = (const float*)d_in[15];
  const float* wse1  = (const float*)d_in[16];
  const float* bse1  = (const float*)d_in[17];
  const float* bnses = (const float*)d_in[18];
  const float* bnseb = (const float*)d_in[19];
  const float* wse2  = (const float*)d_in[20];
  const float* bse2  = (const float*)d_in[21];

  float* ws = (float*)d_ws;
  // layout (float units); wrbuf aliases actbf (actbf dead before w-gemm writes)
  float* kbuf           = ws;                                   // 6291456
  float* vbuf           = ws + 6291456;                         // 6291456
  unsigned short* ebf   = (unsigned short*)(ws + 12582912);     // hi[2b][12][n][8] + lo (6291456 sh)
  unsigned short* actbf = (unsigned short*)(ws + 15728640);     // [2b][48][n][8] (12582912 sh)
  float* wrbuf          = ws + 15728640;                        // 7077888 (aliases actbf)
  unsigned short* apk1  = (unsigned short*)(ws + 22806528);     // 258048 sh
  unsigned short* apkV  = (unsigned short*)(ws + 22935552);     // 36864 sh
  unsigned short* apkE  = (unsigned short*)(ws + 22953984);     // 36864 sh
  unsigned short* apkW  = (unsigned short*)(ws + 22972416);     // 21504 sh
  float* gsums          = ws + 22983168;                        // 96
  float* gap            = ws + 22983264;                        // 384
  float* attnb          = ws + 22983648;                        // 768
  float* x2             = (float*)d_out;

  hipMemsetAsync(gsums, 0, 96 * sizeof(float), stream);

  prep_w<<<dim3(1008), 256, 0, stream>>>(wkey, apk1);
  prep_x<<<dim3(3072), 256, 0, stream>>>(x, actbf);
  pack_a<<<dim3(144), 256, 0, stream>>>(wc1, apkV, 192, 192);
  pack_a<<<dim3(144), 256, 0, stream>>>(we1, apkE, 96, 384);
  pack_a<<<dim3(84), 256, 0, stream>>>(we2, apkW, 224, 96);   // pad M to 224 (rows>=216 zero)

  k1_mfma<<<dim3(64, 4, 2), 256, 0, stream>>>(actbf, apk1, bn1s, bn1b, kbuf, actbf);
  // v = bn3(w_c1 @ x):        K=192 (KCH 6), M=192 (MT 12), fp32 planar out
  gemm_mfma<6, 12, 1, 0, 48><<<dim3(256, 1, 2), 256, 0, stream>>>(
      apkV, actbf, bn3s, bn3b, vbuf, nullptr, 192);
  // e = relu(bn2(w_e1 @ [x;k])): K=384 (KCH 12), M=96 (MT 6), bf16 hi/lo out
  gemm_mfma<12, 6, 0, 0, 48><<<dim3(256, 1, 2), 256, 0, stream>>>(
      apkE, actbf, bn2s, bn2b, nullptr, ebf, 96);
  // wraw = w_e2 @ e + b_e2:   K=96 (KCH 3), M=216 (MT 14), split-B (e hi+lo), fp32 out
  gemm_mfma<3, 14, 2, 1, 12><<<dim3(256, 1, 2), 256, 0, stream>>>(
      apkW, ebf, nullptr, be2, wrbuf, nullptr, 216);

  k3b_gnstats<<<dim3(8, 24, 2), 256, 0, stream>>>(wrbuf, gsums);
  k4_dynconv<<<dim3(16, 8, 16), 256, 0, stream>>>(wrbuf, vbuf, gsums, gns, gnb, bn4s, bn4b, x2);
  k5a_gap<<<dim3(384), 256, 0, stream>>>(x2, kbuf, gap);
  k5b_se<<<dim3(1), 256, 0, stream>>>(gap, wse1, bse1, bnses, bnseb, wse2, bse2, attnb);
  k6_combine<<<dim3(6144), 256, 0, stream>>>(kbuf, attnb, (float*)d_out);
}